// Round 1
// baseline (800.202 us; speedup 1.0000x reference)
//
#include <hip/hip_runtime.h>

// Problem constants (from reference)
#define B_    128
#define P_    16
#define NP_   256
#define EP_   1280
#define EPG_  2048
#define ODIM_ 256
#define NH_   128

// ---------------------------------------------------------------------------
// Stage A: per-plane-graph encoder. One block (256 threads) per graph (2048).
// Layer-1 GAT is rank-1 (input dim = 1): per node we only track f, S0, S1 and
// derive BN via scalar moments. Layer-2 / decoder are dense 128x32 dots with
// weights broadcast from LDS.
// ---------------------------------------------------------------------------
struct SmemA {
  float f[256];
  float el2[256];
  float er2[256];
  float abg[3][128];          // alpha/beta/gamma for on-the-fly h1
  float4 wbuf[128*8];         // 16 KB: W2, then res2, then dW1^T
  float4 zbuf[256*9];         // 36 KB: rows padded to 36 floats (bank spread)
  union {
    struct { int cnt[256]; int wtot[4]; unsigned short esrc[1280]; } e;  // edge sort
    struct { float red[4][128]; } d;       // decoder BN partials
    struct { float red[2][8][32]; } l2;    // layer-2 BN / rep partials
  } u;
  float al2v[32], ar2v[32], b2v[32];
  float scA[32], shA[32];
  float dscA[128], dshA[128];
  float db1v[128], dW2v[128];
  float r8[4][8];
  float stat[8];
  float wA[2], wB[2];
};

__global__ __launch_bounds__(256) void plane_enc(
    const float* __restrict__ feat, const int* __restrict__ esrcg, const int* __restrict__ edstg,
    const float* __restrict__ W1, const float* __restrict__ al1, const float* __restrict__ ar1,
    const float* __restrict__ res1, const float* __restrict__ b1, const float* __restrict__ g1,
    const float* __restrict__ be1,
    const float* __restrict__ W2, const float* __restrict__ al2, const float* __restrict__ ar2,
    const float* __restrict__ res2, const float* __restrict__ b2, const float* __restrict__ g2,
    const float* __restrict__ be2,
    const float* __restrict__ dW1, const float* __restrict__ db1, const float* __restrict__ dg,
    const float* __restrict__ dbe, const float* __restrict__ dW2, const float* __restrict__ db2,
    float* __restrict__ rep_out, float* __restrict__ rloss_out)
{
  __shared__ SmemA s;
  const int g = blockIdx.x;
  const int p = g & 15;
  const int t = threadIdx.x;
  const int lane = t & 63, wv = t >> 6;

  // ---- phase 0: loads + counting-sort edges by dst -------------------------
  s.f[t] = feat[g*NP_ + t];
  if (t < 32) {
    s.al2v[t] = al2[p*32 + t];
    s.ar2v[t] = ar2[p*32 + t];
    s.b2v[t]  = b2[p*32 + t];
  }
  s.u.e.cnt[t] = 0;
  __syncthreads();

  const int* gs = esrcg + g*EP_;
  const int* gd = edstg + g*EP_;
  for (int k = t; k < EP_; k += 256) atomicAdd(&s.u.e.cnt[gd[k]], 1);
  __syncthreads();

  int v = s.u.e.cnt[t];
  int incl = v;
  #pragma unroll
  for (int off = 1; off < 64; off <<= 1) {
    int n = __shfl_up(incl, off, 64);
    if (lane >= off) incl += n;
  }
  if (lane == 63) s.u.e.wtot[wv] = incl;
  __syncthreads();
  int woff = 0;
  for (int w = 0; w < wv; w++) woff += s.u.e.wtot[w];
  const int myStart = woff + incl - v;
  const int myDeg = v;
  __syncthreads();
  s.u.e.cnt[t] = myStart;
  __syncthreads();
  for (int k = t; k < EP_; k += 256) {
    int d = gd[k];
    int pos = atomicAdd(&s.u.e.cnt[d], 1);
    s.u.e.esrc[pos] = (unsigned short)gs[k];
  }
  // layer-1 head weights: A_h = sum_d W1[h,d]*al1[h,d] (el2/er2 as scratch)
  if (t < 128) {
    float w1v = W1[p*128 + t];
    s.el2[t] = w1v * al1[p*128 + t];
    s.er2[t] = w1v * ar1[p*128 + t];
  }
  __syncthreads();
  if (t < 2) {
    float a = 0.f, bq = 0.f;
    for (int d2 = 0; d2 < 64; d2++) { a += s.el2[t*64 + d2]; bq += s.er2[t*64 + d2]; }
    s.wA[t] = a; s.wB[t] = bq;
  }
  __syncthreads();

  // ---- layer-1 edge softmax (per-dst gather, rank-1) -----------------------
  const float fi = s.f[t];
  float S0, S1;
  {
    const float wa0 = s.wA[0], wb0 = s.wB[0], wa1 = s.wA[1], wb1 = s.wB[1];
    float m0 = -1e30f, m1 = -1e30f;
    for (int j = 0; j < myDeg; j++) {
      float fs = s.f[s.u.e.esrc[myStart + j]];
      float e0 = wa0*fs + wb0*fi; e0 = e0 > 0.f ? e0 : 0.2f*e0;
      float e1 = wa1*fs + wb1*fi; e1 = e1 > 0.f ? e1 : 0.2f*e1;
      m0 = fmaxf(m0, e0); m1 = fmaxf(m1, e1);
    }
    float ss0 = 0.f, ss1 = 0.f, U0 = 0.f, U1 = 0.f;
    for (int j = 0; j < myDeg; j++) {
      float fs = s.f[s.u.e.esrc[myStart + j]];
      float e0 = wa0*fs + wb0*fi; e0 = e0 > 0.f ? e0 : 0.2f*e0;
      float e1 = wa1*fs + wb1*fi; e1 = e1 > 0.f ? e1 : 0.2f*e1;
      float x0 = __expf(e0 - m0), x1 = __expf(e1 - m1);
      ss0 += x0; U0 += x0*fs;
      ss1 += x1; U1 += x1*fs;
    }
    S0 = U0 / (ss0 + 1e-9f);
    S1 = U1 / (ss1 + 1e-9f);
  }

  // ---- layer-1 BN via scalar moments ---------------------------------------
  {
    float vals[8] = {fi, fi*fi, S0, S0*S0, S0*fi, S1, S1*S1, S1*fi};
    #pragma unroll
    for (int d2 = 32; d2 > 0; d2 >>= 1) {
      #pragma unroll
      for (int q = 0; q < 8; q++) vals[q] += __shfl_down(vals[q], d2, 64);
    }
    if (lane == 0) {
      #pragma unroll
      for (int q = 0; q < 8; q++) s.r8[wv][q] = vals[q];
    }
  }
  __syncthreads();
  if (t < 8) s.stat[t] = (s.r8[0][t] + s.r8[1][t] + s.r8[2][t] + s.r8[3][t]) * (1.f/256.f);
  __syncthreads();
  if (t < 128) {
    float mf = s.stat[0], ef2 = s.stat[1];
    int hh = t >> 6;
    float mS = s.stat[2 + 3*hh], eS2 = s.stat[3 + 3*hh], eSf = s.stat[4 + 3*hh];
    float varS = eS2 - mS*mS;
    float varf = ef2 - mf*mf;
    float cov  = eSf - mS*mf;
    float Wv = W1[p*128 + t], Rv = res1[p*128 + t], Bv = b1[p*128 + t];
    float mu  = Wv*mS + Rv*mf + Bv;
    float var = Wv*Wv*varS + Rv*Rv*varf + 2.f*Wv*Rv*cov;
    float gn  = g1[p*128 + t] * rsqrtf(var + 1e-5f);
    s.abg[0][t] = gn * Wv;
    s.abg[1][t] = gn * Rv;
    s.abg[2][t] = gn * (Bv - mu) + be1[p*128 + t];
  }
  __syncthreads();
  {
    const float* W2g = W2 + p*4096;
    for (int q = 0; q < 16; q++) { int idx = t + 256*q; ((float*)s.wbuf)[idx] = W2g[idx]; }
  }
  __syncthreads();

  // ---- z2 = h1 @ W2 (h1 on the fly), attn logits, store z2 -----------------
  float acc[32];
  {
    #pragma unroll
    for (int d2 = 0; d2 < 32; d2++) acc[d2] = 0.f;
    for (int c = 0; c < 128; c++) {
      float Sc = (c < 64) ? S0 : S1;
      float h1 = fmaxf(s.abg[0][c]*Sc + s.abg[1][c]*fi + s.abg[2][c], 0.f);
      const float4* wr = &s.wbuf[c*8];
      #pragma unroll
      for (int q = 0; q < 8; q++) {
        float4 w4 = wr[q];
        acc[4*q+0] += h1*w4.x; acc[4*q+1] += h1*w4.y;
        acc[4*q+2] += h1*w4.z; acc[4*q+3] += h1*w4.w;
      }
    }
    float el = 0.f, er = 0.f;
    #pragma unroll
    for (int d2 = 0; d2 < 32; d2++) { el += acc[d2]*s.al2v[d2]; er += acc[d2]*s.ar2v[d2]; }
    s.el2[t] = el; s.er2[t] = er;
    float4* zr = &s.zbuf[t*9];
    #pragma unroll
    for (int q = 0; q < 8; q++) zr[q] = make_float4(acc[4*q], acc[4*q+1], acc[4*q+2], acc[4*q+3]);
  }
  __syncthreads();
  {
    const float* Rg = res2 + p*4096;
    for (int q = 0; q < 16; q++) { int idx = t + 256*q; ((float*)s.wbuf)[idx] = Rg[idx]; }
  }
  __syncthreads();

  // ---- res2 path: rr = h1 @ res2 ------------------------------------------
  float rr[32];
  {
    #pragma unroll
    for (int d2 = 0; d2 < 32; d2++) rr[d2] = 0.f;
    for (int c = 0; c < 128; c++) {
      float Sc = (c < 64) ? S0 : S1;
      float h1 = fmaxf(s.abg[0][c]*Sc + s.abg[1][c]*fi + s.abg[2][c], 0.f);
      const float4* wr = &s.wbuf[c*8];
      #pragma unroll
      for (int q = 0; q < 8; q++) {
        float4 w4 = wr[q];
        rr[4*q+0] += h1*w4.x; rr[4*q+1] += h1*w4.y;
        rr[4*q+2] += h1*w4.z; rr[4*q+3] += h1*w4.w;
      }
    }
  }

  // ---- layer-2 edge softmax + aggregate ------------------------------------
  {
    const float eri = s.er2[t];
    float m = -1e30f;
    for (int j = 0; j < myDeg; j++) {
      float e = s.el2[s.u.e.esrc[myStart + j]] + eri;
      e = e > 0.f ? e : 0.2f*e;
      m = fmaxf(m, e);
    }
    float ss = 0.f;
    #pragma unroll
    for (int d2 = 0; d2 < 32; d2++) acc[d2] = 0.f;   // reuse as rst accumulator
    for (int j = 0; j < myDeg; j++) {
      int sj = s.u.e.esrc[myStart + j];
      float e = s.el2[sj] + eri;
      e = e > 0.f ? e : 0.2f*e;
      float x = __expf(e - m);
      ss += x;
      const float4* zr = &s.zbuf[sj*9];
      #pragma unroll
      for (int q = 0; q < 8; q++) {
        float4 z4 = zr[q];
        acc[4*q+0] += x*z4.x; acc[4*q+1] += x*z4.y;
        acc[4*q+2] += x*z4.z; acc[4*q+3] += x*z4.w;
      }
    }
    float inv = 1.f / (ss + 1e-9f);
    #pragma unroll
    for (int d2 = 0; d2 < 32; d2++) acc[d2] = acc[d2]*inv + rr[d2] + s.b2v[d2];
  }
  __syncthreads();   // everyone done reading z2 from zbuf
  {
    float4* zr = &s.zbuf[t*9];
    #pragma unroll
    for (int q = 0; q < 8; q++) zr[q] = make_float4(acc[4*q], acc[4*q+1], acc[4*q+2], acc[4*q+3]);
  }
  __syncthreads();

  // ---- layer-2 BN ----------------------------------------------------------
  {
    int c = t & 31, gq = t >> 5;
    const float* zf = (const float*)s.zbuf;
    float s1 = 0.f, s2 = 0.f;
    for (int j = 0; j < 32; j++) {
      float x = zf[(gq*32 + j)*36 + c];
      s1 += x; s2 += x*x;
    }
    s.u.l2.red[0][gq][c] = s1;
    s.u.l2.red[1][gq][c] = s2;
  }
  __syncthreads();
  if (t < 32) {
    float s1 = 0.f, s2 = 0.f;
    #pragma unroll
    for (int gq = 0; gq < 8; gq++) { s1 += s.u.l2.red[0][gq][t]; s2 += s.u.l2.red[1][gq][t]; }
    float mu = s1 * (1.f/256.f);
    float var = s2 * (1.f/256.f) - mu*mu;
    float a = g2[p*32 + t] * rsqrtf(var + 1e-5f);
    s.scA[t] = a;
    s.shA[t] = be2[p*32 + t] - a*mu;
  }
  __syncthreads();
  #pragma unroll
  for (int d2 = 0; d2 < 32; d2++) acc[d2] = fmaxf(s.scA[d2]*acc[d2] + s.shA[d2], 0.f); // acc = h2 row
  {
    float4* zr = &s.zbuf[t*9];
    #pragma unroll
    for (int q = 0; q < 8; q++) zr[q] = make_float4(acc[4*q], acc[4*q+1], acc[4*q+2], acc[4*q+3]);
  }
  __syncthreads();

  // ---- rep = mean(h2) ------------------------------------------------------
  {
    int c = t & 31, gq = t >> 5;
    const float* zf = (const float*)s.zbuf;
    float s1 = 0.f;
    for (int j = 0; j < 32; j++) s1 += zf[(gq*32 + j)*36 + c];
    s.u.l2.red[0][gq][c] = s1;
  }
  __syncthreads();
  if (t < 32) {
    float s1 = 0.f;
    #pragma unroll
    for (int gq = 0; gq < 8; gq++) s1 += s.u.l2.red[0][gq][t];
    rep_out[g*32 + t] = s1 * (1.f/256.f);   // == plane_rep[b][p*32+t]
  }
  // decoder weights: wbuf <- dW1^T ([c][d]), plus db1/dW2
  {
    const float* Dg = dW1 + p*4096;        // [32][128]
    for (int q = 0; q < 16; q++) {
      int idx = t + 256*q;                 // idx = c*32 + d
      int c = idx >> 5, d2 = idx & 31;
      ((float*)s.wbuf)[idx] = Dg[d2*128 + c];
    }
    if (t < 128) { s.db1v[t] = db1[p*128 + t]; s.dW2v[t] = dW2[p*128 + t]; }
  }
  __syncthreads();

  // ---- decoder BN stats: t = h2 @ dW1 + db1 --------------------------------
  {
    int c = t & 127, gq = t >> 7;
    float4 w[8];
    #pragma unroll
    for (int q = 0; q < 8; q++) w[q] = s.wbuf[c*8 + q];
    float bc = s.db1v[c];
    float s1 = 0.f, s2 = 0.f;
    for (int r = gq*128; r < gq*128 + 128; r++) {
      const float4* zr = &s.zbuf[r*9];
      float tt = bc;
      #pragma unroll
      for (int q = 0; q < 8; q++) {
        float4 z4 = zr[q];
        tt += z4.x*w[q].x + z4.y*w[q].y + z4.z*w[q].z + z4.w*w[q].w;
      }
      s1 += tt; s2 += tt*tt;
    }
    s.u.d.red[gq][c]     = s1;
    s.u.d.red[2 + gq][c] = s2;
  }
  __syncthreads();
  if (t < 128) {
    float s1 = s.u.d.red[0][t] + s.u.d.red[1][t];
    float s2 = s.u.d.red[2][t] + s.u.d.red[3][t];
    float mu = s1 * (1.f/256.f);
    float var = s2 * (1.f/256.f) - mu*mu;
    float a = dg[p*128 + t] * rsqrtf(var + 1e-5f);
    s.dscA[t] = a;
    s.dshA[t] = dbe[p*128 + t] - a*mu;
  }
  __syncthreads();

  // ---- recon + rloss -------------------------------------------------------
  {
    float rc = db2[p];
    for (int c = 0; c < 128; c++) {
      const float4* wr = &s.wbuf[c*8];
      float tt = s.db1v[c];
      #pragma unroll
      for (int q = 0; q < 8; q++) {
        float4 w4 = wr[q];
        tt += acc[4*q]*w4.x + acc[4*q+1]*w4.y + acc[4*q+2]*w4.z + acc[4*q+3]*w4.w;
      }
      float dv = fmaxf(s.dscA[c]*tt + s.dshA[c], 0.f);
      rc += dv * s.dW2v[c];
    }
    float diff = rc - fi;
    float sq = diff*diff;
    #pragma unroll
    for (int d2 = 32; d2 > 0; d2 >>= 1) sq += __shfl_down(sq, d2, 64);
    if (lane == 0) s.r8[wv][0] = sq;
  }
  __syncthreads();
  if (t == 0) {
    float tot = s.r8[0][0] + s.r8[1][0] + s.r8[2][0] + s.r8[3][0];
    atomicAdd(rloss_out, tot * (1.f/(256.f*2048.f)));
  }
}

// ---------------------------------------------------------------------------
// Stage B: patient-level graph net on [128,128] tensors.
// ---------------------------------------------------------------------------
__global__ __launch_bounds__(256) void k_deg(const int* __restrict__ ps, const int* __restrict__ pd,
                                             float* __restrict__ deg) {
  __shared__ int co[128], ci[128];
  int t = threadIdx.x;
  if (t < 128) { co[t] = 0; ci[t] = 0; }
  __syncthreads();
  for (int e = t; e < EPG_; e += 256) { atomicAdd(&co[ps[e]], 1); atomicAdd(&ci[pd[e]], 1); }
  __syncthreads();
  if (t < 128) {
    int a = co[t] > 1 ? co[t] : 1;
    int b = ci[t] > 1 ? ci[t] : 1;
    deg[t]       = rsqrtf((float)a);
    deg[128 + t] = rsqrtf((float)b);
  }
}

__global__ __launch_bounds__(128) void k_b1(const float* __restrict__ orig, const float* __restrict__ rep,
                                            const float* __restrict__ ftW, const float* __restrict__ ftb,
                                            float* __restrict__ u0) {
  __shared__ float x[768];
  int b = blockIdx.x, t = threadIdx.x;
  for (int j = t; j < 256; j += 128) x[j] = orig[b*256 + j];
  for (int j = t; j < 512; j += 128) x[256 + j] = rep[b*512 + j];
  __syncthreads();
  float a = ftb[t];
  for (int k = 0; k < 768; k++) a += x[k] * ftW[k*128 + t];
  u0[b*128 + t] = a;
}

__global__ __launch_bounds__(128) void k_b2(const float* __restrict__ u0, const float* __restrict__ g,
                                            const float* __restrict__ be, float* __restrict__ h,
                                            float* __restrict__ hsum) {
  int c = threadIdx.x;
  float s1 = 0.f, s2 = 0.f;
  for (int r = 0; r < 128; r++) { float v = u0[r*128 + c]; s1 += v; s2 += v*v; }
  float mu = s1*(1.f/128.f), var = s2*(1.f/128.f) - mu*mu;
  float a = g[c]*rsqrtf(var + 1e-5f);
  float sh = be[c] - a*mu;
  for (int r = 0; r < 128; r++) {
    float hv = fmaxf(a*u0[r*128 + c] + sh, 0.f);
    h[r*128 + c] = hv; hsum[r*128 + c] = hv;
  }
}

__global__ __launch_bounds__(256) void k_agg(const float* __restrict__ h, const int* __restrict__ mask,
                                             const int* __restrict__ ps, const int* __restrict__ pd,
                                             const float* __restrict__ deg, float* __restrict__ agg) {
  __shared__ float hh[128*33];
  __shared__ float ag[128*33];
  __shared__ float mk[128];
  int t = threadIdx.x, c0 = blockIdx.x*32;
  if (t < 128) mk[t] = (float)mask[t];
  for (int idx = t; idx < 4096; idx += 256) {
    int r = idx >> 5, c = idx & 31;
    hh[r*33 + c] = h[r*128 + c0 + c] * deg[r];   // hs = h * rsqrt(d_out)
    ag[r*33 + c] = 0.f;
  }
  __syncthreads();
  for (int e = t; e < EPG_; e += 256) {
    int sN = ps[e], dN = pd[e];
    float w = mk[sN]*mk[dN];
    if (w != 0.f) {
      #pragma unroll
      for (int c = 0; c < 32; c++) atomicAdd(&ag[dN*33 + c], w*hh[sN*33 + c]);
    }
  }
  __syncthreads();
  for (int idx = t; idx < 4096; idx += 256) {
    int r = idx >> 5, c = idx & 31;
    agg[r*128 + c0 + c] = ag[r*33 + c] * deg[128 + r];  // * rsqrt(d_in)
  }
}

__global__ __launch_bounds__(256) void k_mm(const float* __restrict__ agg, const float* __restrict__ W,
                                            const float* __restrict__ bias, const float* __restrict__ g,
                                            const float* __restrict__ be,
                                            float* __restrict__ h, float* __restrict__ hsum) {
  __shared__ float red1[8][32], red2[8][32];
  __shared__ float sc[32], sh[32];
  int t = threadIdx.x, c0 = blockIdx.x*32;
  int c = t & 31, gq = t >> 5;
  float o[16];
  float bv = bias[c0 + c];
  #pragma unroll
  for (int j = 0; j < 16; j++) o[j] = bv;
  for (int k = 0; k < 128; k++) {
    float w = W[k*128 + c0 + c];
    #pragma unroll
    for (int j = 0; j < 16; j++) o[j] += agg[(gq*16 + j)*128 + k] * w;
  }
  float s1 = 0.f, s2 = 0.f;
  #pragma unroll
  for (int j = 0; j < 16; j++) { s1 += o[j]; s2 += o[j]*o[j]; }
  red1[gq][c] = s1; red2[gq][c] = s2;
  __syncthreads();
  if (t < 32) {
    float a1 = 0.f, a2 = 0.f;
    #pragma unroll
    for (int q = 0; q < 8; q++) { a1 += red1[q][t]; a2 += red2[q][t]; }
    float mu = a1*(1.f/128.f), var = a2*(1.f/128.f) - mu*mu;
    float a = g[c0 + t]*rsqrtf(var + 1e-5f);
    sc[t] = a; sh[t] = be[c0 + t] - a*mu;
  }
  __syncthreads();
  #pragma unroll
  for (int j = 0; j < 16; j++) {
    int idx = (gq*16 + j)*128 + c0 + c;
    float hn = fmaxf(sc[c]*o[j] + sh[c], 0.f);
    float hnew = hn + h[idx];
    h[idx] = hnew;
    hsum[idx] += hnew;
  }
}

__global__ __launch_bounds__(256) void k_cls(const float* __restrict__ hsum,
    const float* __restrict__ c1W, const float* __restrict__ c1b,
    const float* __restrict__ lng, const float* __restrict__ lnbe,
    const float* __restrict__ c2W, const float* __restrict__ c2b,
    const float* __restrict__ rloss, float* __restrict__ out) {
  __shared__ float w[128*64];
  __shared__ float red[128][4];
  int t = threadIdx.x;
  for (int idx = t; idx < 8192; idx += 256) w[idx] = c1W[idx];
  __syncthreads();
  int r = t >> 1, cg = t & 1;
  float z[32];
  #pragma unroll
  for (int j = 0; j < 32; j++) z[j] = c1b[cg*32 + j];
  for (int k = 0; k < 128; k++) {
    float hv = hsum[r*128 + k] * 0.25f;     // h = h_sum / 4
    #pragma unroll
    for (int j = 0; j < 32; j++) z[j] += hv * w[k*64 + cg*32 + j];
  }
  float s1 = 0.f, s2 = 0.f;
  #pragma unroll
  for (int j = 0; j < 32; j++) { s1 += z[j]; s2 += z[j]*z[j]; }
  red[r][cg] = s1; red[r][2 + cg] = s2;
  __syncthreads();
  float mu = (red[r][0] + red[r][1]) * (1.f/64.f);
  float var = (red[r][2] + red[r][3]) * (1.f/64.f) - mu*mu;
  float rs = rsqrtf(var + 1e-5f);
  float l0 = 0.f, l1 = 0.f;
  #pragma unroll
  for (int j = 0; j < 32; j++) {
    int cc = cg*32 + j;
    float zn = fmaxf(lng[cc]*(z[j] - mu)*rs + lnbe[cc], 0.f);
    l0 += zn * c2W[cc*2];
    l1 += zn * c2W[cc*2 + 1];
  }
  __syncthreads();
  red[r][cg] = l0; red[r][2 + cg] = l1;
  __syncthreads();
  if (cg == 0) {
    out[r*2]     = red[r][0] + red[r][1] + c2b[0];
    out[r*2 + 1] = red[r][2] + red[r][3] + c2b[1];
  }
  if (t == 0) out[256] = rloss[0];
}

// ---------------------------------------------------------------------------
extern "C" void kernel_launch(void* const* d_in, const int* in_sizes, int n_in,
                              void* d_out, int out_size, void* d_ws, size_t ws_size,
                              hipStream_t stream) {
  (void)in_sizes; (void)n_in; (void)out_size; (void)ws_size;
  const float* plane_feat  = (const float*)d_in[0];
  const int*   plane_src   = (const int*)d_in[1];
  const int*   plane_dst   = (const int*)d_in[2];
  const int*   patient_src = (const int*)d_in[3];
  const int*   patient_dst = (const int*)d_in[4];
  const float* orig        = (const float*)d_in[5];
  const int*   mask        = (const int*)d_in[6];
  const float* W1   = (const float*)d_in[7];
  const float* al1  = (const float*)d_in[8];
  const float* ar1  = (const float*)d_in[9];
  const float* res1 = (const float*)d_in[10];
  const float* b1   = (const float*)d_in[11];
  const float* g1   = (const float*)d_in[12];
  const float* be1  = (const float*)d_in[13];
  const float* W2   = (const float*)d_in[14];
  const float* al2  = (const float*)d_in[15];
  const float* ar2  = (const float*)d_in[16];
  const float* res2 = (const float*)d_in[17];
  const float* b2   = (const float*)d_in[18];
  const float* g2   = (const float*)d_in[19];
  const float* be2  = (const float*)d_in[20];
  const float* dW1  = (const float*)d_in[21];
  const float* db1  = (const float*)d_in[22];
  const float* dg   = (const float*)d_in[23];
  const float* dbe  = (const float*)d_in[24];
  const float* dW2  = (const float*)d_in[25];
  const float* db2  = (const float*)d_in[26];
  const float* ftW  = (const float*)d_in[27];
  const float* ftb  = (const float*)d_in[28];
  const float* ftg  = (const float*)d_in[29];
  const float* ftbe = (const float*)d_in[30];
  const float* gcW  = (const float*)d_in[31];
  const float* gcb  = (const float*)d_in[32];
  const float* gbng = (const float*)d_in[33];
  const float* gbnbe= (const float*)d_in[34];
  const float* c1W  = (const float*)d_in[35];
  const float* c1b  = (const float*)d_in[36];
  const float* lng  = (const float*)d_in[37];
  const float* lnbe = (const float*)d_in[38];
  const float* c2W  = (const float*)d_in[39];
  const float* c2b  = (const float*)d_in[40];

  float* ws   = (float*)d_ws;             // needs ~526 KB of d_ws
  float* rep  = ws;                       // [128][512]
  float* u0   = ws + 65536;               // [128][128]
  float* h    = ws + 81920;               // [128][128]
  float* hsum = ws + 98304;               // [128][128]
  float* agg  = ws + 114688;              // [128][128]
  float* deg  = ws + 131072;              // [256]
  float* rl   = ws + 131328;              // [1]
  float* outp = (float*)d_out;

  hipMemsetAsync(rl, 0, sizeof(float), stream);
  plane_enc<<<2048, 256, 0, stream>>>(plane_feat, plane_src, plane_dst,
      W1, al1, ar1, res1, b1, g1, be1, W2, al2, ar2, res2, b2, g2, be2,
      dW1, db1, dg, dbe, dW2, db2, rep, rl);
  k_deg<<<1, 256, 0, stream>>>(patient_src, patient_dst, deg);
  k_b1<<<128, 128, 0, stream>>>(orig, rep, ftW, ftb, u0);
  k_b2<<<1, 128, 0, stream>>>(u0, ftg, ftbe, h, hsum);
  for (int i = 0; i < 3; i++) {
    k_agg<<<4, 256, 0, stream>>>(h, mask, patient_src, patient_dst, deg, agg);
    k_mm<<<4, 256, 0, stream>>>(agg, gcW + i*16384, gcb + i*128,
                                gbng + i*128, gbnbe + i*128, h, hsum);
  }
  k_cls<<<1, 256, 0, stream>>>(hsum, c1W, c1b, lng, lnbe, c2W, c2b, rl, outp);
}

// Round 2
// 515.394 us; speedup vs baseline: 1.5526x; 1.5526x over previous
//
#include <hip/hip_runtime.h>

#define B_    128
#define P_    16
#define NP_   256
#define EP_   1280
#define EPG_  2048
#define ODIM_ 256
#define NH_   128

typedef __attribute__((ext_vector_type(8))) short s8_t;
typedef __attribute__((ext_vector_type(4))) float f4_t;

__device__ __forceinline__ unsigned short f2b(float x) {
  unsigned u = __builtin_bit_cast(unsigned, x);
  u = (u + 0x7fffu + ((u >> 16) & 1u)) >> 16;
  return (unsigned short)u;
}
__device__ __forceinline__ float b2f(short x) {
  unsigned u = ((unsigned)(unsigned short)x) << 16;
  return __builtin_bit_cast(float, u);
}

// ---------------------------------------------------------------------------
// Stage A: one block (256 thr = 4 waves) per plane graph (2048 graphs).
// Layer-1 GAT is rank-1 (input dim 1): per node only (f, S0, S1); BN1 via
// scalar moments. Dense matmuls run on MFMA bf16 16x16x32:
//   matmul1: h1[256x128] @ [W2|res2][128x64]   (A-frags built in registers)
//   matmul2: h2[256x32]  @ dW1[32x128]         (BN+recon in C-frag epilogue)
// Biases b1-cancellation: bias added before BN cancels (BN(x+c)=BN(x)).
// ---------------------------------------------------------------------------
struct SmemA {
  float f[256];
  float S0a[256], S1a[256];
  float el2[256], er2[256];
  float abg0[128], abg1[128], abg2[128];
  float al2v[32], ar2v[32];
  __align__(16) unsigned short wT[64 * 136];   // WcT bf16 [64][128+8pad]; later dW1T [128][40]
  __align__(16) unsigned short z2[256 * 72];   // bf16 [256][64+8pad]; later h2 bf16
  int cnt[256]; int wtot[4];
  unsigned short esrc[1280];
  float redf[512];
  float scA[32], shA[32];
  float dscA[64], dshA[64];
  float dW2v[128];
  float r8[4][8]; float stat[8]; float wA[2], wB[2];
  float rlacc;
};

__global__ __launch_bounds__(256) void plane_enc(
    const float* __restrict__ feat, const int* __restrict__ esrcg, const int* __restrict__ edstg,
    const float* __restrict__ W1, const float* __restrict__ al1, const float* __restrict__ ar1,
    const float* __restrict__ res1, const float* __restrict__ b1, const float* __restrict__ g1,
    const float* __restrict__ be1,
    const float* __restrict__ W2, const float* __restrict__ al2, const float* __restrict__ ar2,
    const float* __restrict__ res2, const float* __restrict__ g2, const float* __restrict__ be2,
    const float* __restrict__ dW1, const float* __restrict__ dg, const float* __restrict__ dbe,
    const float* __restrict__ dW2, const float* __restrict__ db2,
    float* __restrict__ rep_out, float* __restrict__ rloss_out)
{
  __shared__ SmemA s;
  const int g = blockIdx.x;
  const int p = g & 15;
  const int t = threadIdx.x;
  const int lane = t & 63, wv = t >> 6;
  const int l15 = lane & 15, quad = lane >> 4;

  // ---- phase 0: loads ------------------------------------------------------
  s.f[t] = feat[g * NP_ + t];
  if (t < 32) { s.al2v[t] = al2[p * 32 + t]; s.ar2v[t] = ar2[p * 32 + t]; }
  if (t == 0) s.rlacc = 0.f;
  s.cnt[t] = 0;
  __syncthreads();

  // ---- counting-sort edges by dst ------------------------------------------
  const int* gs = esrcg + g * EP_;
  const int* gd = edstg + g * EP_;
  for (int k = t; k < EP_; k += 256) atomicAdd(&s.cnt[gd[k]], 1);
  __syncthreads();
  int v = s.cnt[t];
  int incl = v;
  #pragma unroll
  for (int off = 1; off < 64; off <<= 1) {
    int n = __shfl_up(incl, off, 64);
    if (lane >= off) incl += n;
  }
  if (lane == 63) s.wtot[wv] = incl;
  __syncthreads();
  int woff = 0;
  for (int w = 0; w < wv; w++) woff += s.wtot[w];
  const int myStart = woff + incl - v;
  const int myDeg = v;
  __syncthreads();
  s.cnt[t] = myStart;
  __syncthreads();
  for (int k = t; k < EP_; k += 256) {
    int d = gd[k];
    int pos = atomicAdd(&s.cnt[d], 1);
    s.esrc[pos] = (unsigned short)gs[k];
  }
  // stage WcT = [W2|res2]^T bf16, padded rows of 136
  {
    const float* W2g = W2 + p * 4096;
    const float* Rg  = res2 + p * 4096;
    for (int q = 0; q < 16; q++) {
      int idx = t + 256 * q;                 // idx = k*32 + n
      int k = idx >> 5, n = idx & 31;
      s.wT[n * 136 + k]        = f2b(W2g[idx]);
      s.wT[(n + 32) * 136 + k] = f2b(Rg[idx]);
    }
  }
  // layer-1 head scalars: A_h = sum_d W1[h,d]*al1[h,d] (el2/er2 as scratch)
  if (t < 128) {
    float w1v = W1[p * 128 + t];
    s.el2[t] = w1v * al1[p * 128 + t];
    s.er2[t] = w1v * ar1[p * 128 + t];
  }
  __syncthreads();
  if (t < 2) {
    float a = 0.f, bq = 0.f;
    for (int d2 = 0; d2 < 64; d2++) { a += s.el2[t * 64 + d2]; bq += s.er2[t * 64 + d2]; }
    s.wA[t] = a; s.wB[t] = bq;
  }
  __syncthreads();

  // ---- layer-1 rank-1 edge softmax -----------------------------------------
  const float fi = s.f[t];
  float S0, S1;
  {
    const float wa0 = s.wA[0], wb0 = s.wB[0], wa1 = s.wA[1], wb1 = s.wB[1];
    float m0 = -1e30f, m1 = -1e30f;
    for (int j = 0; j < myDeg; j++) {
      float fs = s.f[s.esrc[myStart + j]];
      float e0 = wa0 * fs + wb0 * fi; e0 = e0 > 0.f ? e0 : 0.2f * e0;
      float e1 = wa1 * fs + wb1 * fi; e1 = e1 > 0.f ? e1 : 0.2f * e1;
      m0 = fmaxf(m0, e0); m1 = fmaxf(m1, e1);
    }
    float ss0 = 0.f, ss1 = 0.f, U0 = 0.f, U1 = 0.f;
    for (int j = 0; j < myDeg; j++) {
      float fs = s.f[s.esrc[myStart + j]];
      float e0 = wa0 * fs + wb0 * fi; e0 = e0 > 0.f ? e0 : 0.2f * e0;
      float e1 = wa1 * fs + wb1 * fi; e1 = e1 > 0.f ? e1 : 0.2f * e1;
      float x0 = __expf(e0 - m0), x1 = __expf(e1 - m1);
      ss0 += x0; U0 += x0 * fs;
      ss1 += x1; U1 += x1 * fs;
    }
    S0 = U0 / (ss0 + 1e-9f);
    S1 = U1 / (ss1 + 1e-9f);
    s.S0a[t] = S0; s.S1a[t] = S1;
  }

  // ---- layer-1 BN via scalar moments ---------------------------------------
  {
    float vals[8] = {fi, fi * fi, S0, S0 * S0, S0 * fi, S1, S1 * S1, S1 * fi};
    #pragma unroll
    for (int d2 = 32; d2 > 0; d2 >>= 1) {
      #pragma unroll
      for (int q = 0; q < 8; q++) vals[q] += __shfl_down(vals[q], d2, 64);
    }
    if (lane == 0) {
      #pragma unroll
      for (int q = 0; q < 8; q++) s.r8[wv][q] = vals[q];
    }
  }
  __syncthreads();
  if (t < 8) s.stat[t] = (s.r8[0][t] + s.r8[1][t] + s.r8[2][t] + s.r8[3][t]) * (1.f / 256.f);
  __syncthreads();
  if (t < 128) {
    float mf = s.stat[0], ef2 = s.stat[1];
    int hh = t >> 6;
    float mS = s.stat[2 + 3 * hh], eS2 = s.stat[3 + 3 * hh], eSf = s.stat[4 + 3 * hh];
    float varS = eS2 - mS * mS, varf = ef2 - mf * mf, cov = eSf - mS * mf;
    float Wv = W1[p * 128 + t], Rv = res1[p * 128 + t], Bv = b1[p * 128 + t];
    float mu  = Wv * mS + Rv * mf + Bv;
    float var = Wv * Wv * varS + Rv * Rv * varf + 2.f * Wv * Rv * cov;
    float gn  = g1[p * 128 + t] * rsqrtf(var + 1e-5f);
    s.abg0[t] = gn * Wv;
    s.abg1[t] = gn * Rv;
    s.abg2[t] = gn * (Bv - mu) + be1[p * 128 + t];
  }
  __syncthreads();

  // ---- matmul1 (MFMA): C1[256x64] = h1 @ [W2|res2] -------------------------
  {
    f4_t accum[4][4];
    #pragma unroll
    for (int i = 0; i < 4; i++)
      #pragma unroll
      for (int nt = 0; nt < 4; nt++) accum[i][nt] = (f4_t){0.f, 0.f, 0.f, 0.f};

    float fm[4], s0m[4], s1m[4];
    #pragma unroll
    for (int i = 0; i < 4; i++) {
      int m = (wv * 4 + i) * 16 + l15;
      fm[i] = s.f[m]; s0m[i] = s.S0a[m]; s1m[i] = s.S1a[m];
    }
    #pragma unroll
    for (int kt = 0; kt < 4; kt++) {
      int cbase = kt * 32 + quad * 8;
      float a0[8], a1[8], a2[8];
      #pragma unroll
      for (int j = 0; j < 8; j++) {
        a0[j] = s.abg0[cbase + j]; a1[j] = s.abg1[cbase + j]; a2[j] = s.abg2[cbase + j];
      }
      s8_t afr[4];
      #pragma unroll
      for (int i = 0; i < 4; i++) {
        float Sm = (kt < 2) ? s0m[i] : s1m[i];
        union { s8_t v; unsigned short u[8]; } fu;
        #pragma unroll
        for (int j = 0; j < 8; j++) {
          float h = fmaxf(fmaf(a0[j], Sm, fmaf(a1[j], fm[i], a2[j])), 0.f);
          fu.u[j] = f2b(h);
        }
        afr[i] = fu.v;
      }
      s8_t bfr[4];
      #pragma unroll
      for (int nt = 0; nt < 4; nt++)
        bfr[nt] = *(const s8_t*)&s.wT[(nt * 16 + l15) * 136 + cbase];
      #pragma unroll
      for (int i = 0; i < 4; i++)
        #pragma unroll
        for (int nt = 0; nt < 4; nt++)
          accum[i][nt] = __builtin_amdgcn_mfma_f32_16x16x32_bf16(afr[i], bfr[nt], accum[i][nt], 0, 0, 0);
    }
    // C-write: col = nt*16 + (lane&15), row = quad*4 + r  (verified layout)
    #pragma unroll
    for (int i = 0; i < 4; i++) {
      int mBase = (wv * 4 + i) * 16 + quad * 4;
      #pragma unroll
      for (int nt = 0; nt < 4; nt++) {
        int col = nt * 16 + l15;
        #pragma unroll
        for (int r = 0; r < 4; r++)
          s.z2[(mBase + r) * 72 + col] = f2b(accum[i][nt][r]);
      }
    }
  }
  __syncthreads();

  // ---- P4: attn logits el2/er2, rr regs; stage dW1T ------------------------
  float rr[32];
  {
    const s8_t* zr = (const s8_t*)&s.z2[t * 72];
    float el = 0.f, er = 0.f;
    #pragma unroll
    for (int q = 0; q < 4; q++) {
      s8_t vz = zr[q];
      #pragma unroll
      for (int j = 0; j < 8; j++) {
        float zv = b2f(vz[j]);
        el += zv * s.al2v[q * 8 + j];
        er += zv * s.ar2v[q * 8 + j];
      }
    }
    s.el2[t] = el; s.er2[t] = er;
    #pragma unroll
    for (int q = 0; q < 4; q++) {
      s8_t vz = zr[4 + q];
      #pragma unroll
      for (int j = 0; j < 8; j++) rr[q * 8 + j] = b2f(vz[j]);
    }
  }
  {
    const float* Dg = dW1 + p * 4096;          // [32][128]
    for (int q = 0; q < 16; q++) {
      int idx = t + 256 * q;
      int k = idx >> 7, n = idx & 127;
      s.wT[n * 40 + k] = f2b(Dg[idx]);
    }
    if (t < 128) s.dW2v[t] = dW2[p * 128 + t];
  }
  const float db2v = db2[p];
  __syncthreads();

  // ---- layer-2 edge softmax + aggregate ------------------------------------
  float hrow[32];
  {
    const float eri = s.er2[t];
    float m = -1e30f;
    for (int j = 0; j < myDeg; j++) {
      float e = s.el2[s.esrc[myStart + j]] + eri;
      e = e > 0.f ? e : 0.2f * e;
      m = fmaxf(m, e);
    }
    float ss = 0.f;
    #pragma unroll
    for (int d2 = 0; d2 < 32; d2++) hrow[d2] = 0.f;
    for (int j = 0; j < myDeg; j++) {
      int sj = s.esrc[myStart + j];
      float e = s.el2[sj] + eri;
      e = e > 0.f ? e : 0.2f * e;
      float x = __expf(e - m);
      ss += x;
      const s8_t* zr = (const s8_t*)&s.z2[sj * 72];
      #pragma unroll
      for (int q = 0; q < 4; q++) {
        s8_t vz = zr[q];
        #pragma unroll
        for (int jj = 0; jj < 8; jj++) hrow[q * 8 + jj] += x * b2f(vz[jj]);
      }
    }
    float inv = 1.f / (ss + 1e-9f);
    #pragma unroll
    for (int d2 = 0; d2 < 32; d2++) hrow[d2] = hrow[d2] * inv + rr[d2];
  }
  __syncthreads();                // all done reading z2
  #pragma unroll
  for (int d2 = 0; d2 < 32; d2++) s.z2[t * 72 + d2] = f2b(hrow[d2]);  // pre-BN bf16
  __syncthreads();

  // ---- layer-2 BN + relu + rep + h2 bf16 -----------------------------------
  {
    int c = t & 31, gq = t >> 5;
    float s1 = 0.f, s2 = 0.f;
    for (int j = 0; j < 32; j++) {
      float vz = b2f((short)s.z2[(gq * 32 + j) * 72 + c]);
      s1 += vz; s2 += vz * vz;
    }
    s.redf[t] = s1; s.redf[256 + t] = s2;
  }
  __syncthreads();
  if (t < 32) {
    float s1 = 0.f, s2 = 0.f;
    #pragma unroll
    for (int q = 0; q < 8; q++) { s1 += s.redf[q * 32 + t]; s2 += s.redf[256 + q * 32 + t]; }
    float mu = s1 * (1.f / 256.f);
    float var = s2 * (1.f / 256.f) - mu * mu;
    float a = g2[p * 32 + t] * rsqrtf(var + 1e-5f);
    s.scA[t] = a; s.shA[t] = be2[p * 32 + t] - a * mu;
  }
  __syncthreads();
  {
    int c = t & 31, gq = t >> 5;
    float a = s.scA[c], bb = s.shA[c];
    float s1 = 0.f;
    for (int j = 0; j < 32; j++) {
      int ad = (gq * 32 + j) * 72 + c;
      float vz = b2f((short)s.z2[ad]);
      float hv = fmaxf(a * vz + bb, 0.f);
      s.z2[ad] = f2b(hv);
      s1 += hv;
    }
    s.redf[t] = s1;
  }
  __syncthreads();
  if (t < 32) {
    float s1 = 0.f;
    #pragma unroll
    for (int q = 0; q < 8; q++) s1 += s.redf[q * 32 + t];
    rep_out[g * 32 + t] = s1 * (1.f / 256.f);
  }
  __syncthreads();

  // ---- matmul2 (MFMA) + decoder BN + recon ---------------------------------
  {
    s8_t afr2[4];
    #pragma unroll
    for (int i = 0; i < 4; i++)
      afr2[i] = *(const s8_t*)&s.z2[((wv * 4 + i) * 16 + l15) * 72 + quad * 8];
    float rAcc[4][4];
    #pragma unroll
    for (int i = 0; i < 4; i++)
      #pragma unroll
      for (int r = 0; r < 4; r++) rAcc[i][r] = 0.f;

    for (int half = 0; half < 2; half++) {
      __syncthreads();
      s.redf[t] = 0.f; s.redf[256 + t] = 0.f;
      __syncthreads();
      f4_t acc2[4][4];
      #pragma unroll
      for (int i = 0; i < 4; i++)
        #pragma unroll
        for (int nt = 0; nt < 4; nt++) acc2[i][nt] = (f4_t){0.f, 0.f, 0.f, 0.f};
      s8_t bfr[4];
      #pragma unroll
      for (int nt = 0; nt < 4; nt++)
        bfr[nt] = *(const s8_t*)&s.wT[(half * 64 + nt * 16 + l15) * 40 + quad * 8];
      #pragma unroll
      for (int i = 0; i < 4; i++)
        #pragma unroll
        for (int nt = 0; nt < 4; nt++)
          acc2[i][nt] = __builtin_amdgcn_mfma_f32_16x16x32_bf16(afr2[i], bfr[nt], acc2[i][nt], 0, 0, 0);
      // per-column stats over 256 rows
      #pragma unroll
      for (int nt = 0; nt < 4; nt++) {
        float s1 = 0.f, s2 = 0.f;
        #pragma unroll
        for (int i = 0; i < 4; i++)
          #pragma unroll
          for (int r = 0; r < 4; r++) { float vv = acc2[i][nt][r]; s1 += vv; s2 += vv * vv; }
        atomicAdd(&s.redf[nt * 16 + l15], s1);
        atomicAdd(&s.redf[256 + nt * 16 + l15], s2);
      }
      __syncthreads();
      if (t < 64) {
        int col = half * 64 + t;
        float mu = s.redf[t] * (1.f / 256.f);
        float var = s.redf[256 + t] * (1.f / 256.f) - mu * mu;
        float a = dg[p * 128 + col] * rsqrtf(var + 1e-5f);
        s.dscA[t] = a; s.dshA[t] = dbe[p * 128 + col] - a * mu;
      }
      __syncthreads();
      #pragma unroll
      for (int nt = 0; nt < 4; nt++) {
        int cl = nt * 16 + l15;
        float a = s.dscA[cl], bb = s.dshA[cl], w2 = s.dW2v[half * 64 + cl];
        #pragma unroll
        for (int i = 0; i < 4; i++)
          #pragma unroll
          for (int r = 0; r < 4; r++) {
            float dv = fmaxf(a * acc2[i][nt][r] + bb, 0.f);
            rAcc[i][r] += dv * w2;
          }
      }
    }
    // reduce recon over the 16 lanes sharing each row; then rloss
    #pragma unroll
    for (int off = 1; off < 16; off <<= 1)
      #pragma unroll
      for (int i = 0; i < 4; i++)
        #pragma unroll
        for (int r = 0; r < 4; r++) rAcc[i][r] += __shfl_xor(rAcc[i][r], off, 64);
    if (l15 == 0) {
      float sq = 0.f;
      #pragma unroll
      for (int i = 0; i < 4; i++)
        #pragma unroll
        for (int r = 0; r < 4; r++) {
          int m = (wv * 4 + i) * 16 + quad * 4 + r;
          float diff = rAcc[i][r] + db2v - s.f[m];
          sq += diff * diff;
        }
      atomicAdd(&s.rlacc, sq);
    }
  }
  __syncthreads();
  if (t == 0) atomicAdd(rloss_out, s.rlacc * (1.f / (256.f * 2048.f)));
}

// ---------------------------------------------------------------------------
// Stage B: patient-level graph net on [128,128] tensors.
// ---------------------------------------------------------------------------
__global__ __launch_bounds__(128) void k_b1(const float* __restrict__ orig, const float* __restrict__ rep,
                                            const float* __restrict__ ftW, const float* __restrict__ ftb,
                                            float* __restrict__ u0) {
  __shared__ float x[768];
  int b = blockIdx.x, t = threadIdx.x;
  for (int j = t; j < 256; j += 128) x[j] = orig[b * 256 + j];
  for (int j = t; j < 512; j += 128) x[256 + j] = rep[b * 512 + j];
  __syncthreads();
  float a = ftb[t];
  #pragma unroll 8
  for (int k = 0; k < 768; k++) a += x[k] * ftW[k * 128 + t];
  u0[b * 128 + t] = a;
}

// fused: structural degrees + BN(ft) + relu  (1024 threads, 1 block)
__global__ __launch_bounds__(1024) void k_b2(const float* __restrict__ u0, const float* __restrict__ g,
                                             const float* __restrict__ be,
                                             const int* __restrict__ ps, const int* __restrict__ pd,
                                             float* __restrict__ h, float* __restrict__ hsum,
                                             float* __restrict__ deg) {
  __shared__ float red1[8][128], red2[8][128];
  __shared__ int co[128], ci[128];
  __shared__ float sc[128], sh[128];
  int t = threadIdx.x, c = t & 127, gq = t >> 7;
  if (t < 128) { co[t] = 0; ci[t] = 0; }
  __syncthreads();
  for (int e = t; e < EPG_; e += 1024) { atomicAdd(&co[ps[e]], 1); atomicAdd(&ci[pd[e]], 1); }
  float s1 = 0.f, s2 = 0.f;
  #pragma unroll
  for (int j = 0; j < 16; j++) { float v = u0[(gq * 16 + j) * 128 + c]; s1 += v; s2 += v * v; }
  red1[gq][c] = s1; red2[gq][c] = s2;
  __syncthreads();
  if (t < 128) {
    float a1 = 0.f, a2 = 0.f;
    #pragma unroll
    for (int q = 0; q < 8; q++) { a1 += red1[q][t]; a2 += red2[q][t]; }
    float mu = a1 * (1.f / 128.f), var = a2 * (1.f / 128.f) - mu * mu;
    float a = g[t] * rsqrtf(var + 1e-5f);
    sc[t] = a; sh[t] = be[t] - a * mu;
    int da = co[t] > 1 ? co[t] : 1;
    int db = ci[t] > 1 ? ci[t] : 1;
    deg[t] = rsqrtf((float)da);
    deg[128 + t] = rsqrtf((float)db);
  }
  __syncthreads();
  #pragma unroll
  for (int j = 0; j < 16; j++) {
    int idx = (gq * 16 + j) * 128 + c;
    float hv = fmaxf(sc[c] * u0[idx] + sh[c], 0.f);
    h[idx] = hv; hsum[idx] = hv;
  }
}

__global__ __launch_bounds__(256) void k_agg(const float* __restrict__ h, const int* __restrict__ mask,
                                             const int* __restrict__ ps, const int* __restrict__ pd,
                                             const float* __restrict__ deg, float* __restrict__ agg) {
  __shared__ float hh[128 * 33];
  __shared__ float ag[128 * 33];
  __shared__ float mk[128];
  int t = threadIdx.x, c0 = blockIdx.x * 32;
  if (t < 128) mk[t] = (float)mask[t];
  for (int idx = t; idx < 4096; idx += 256) {
    int r = idx >> 5, c = idx & 31;
    hh[r * 33 + c] = h[r * 128 + c0 + c] * deg[r];
    ag[r * 33 + c] = 0.f;
  }
  __syncthreads();
  for (int e = t; e < EPG_; e += 256) {
    int sN = ps[e], dN = pd[e];
    float w = mk[sN] * mk[dN];
    if (w != 0.f) {
      #pragma unroll
      for (int c = 0; c < 32; c++) atomicAdd(&ag[dN * 33 + c], w * hh[sN * 33 + c]);
    }
  }
  __syncthreads();
  for (int idx = t; idx < 4096; idx += 256) {
    int r = idx >> 5, c = idx & 31;
    agg[r * 128 + c0 + c] = ag[r * 33 + c] * deg[128 + r];
  }
}

__global__ __launch_bounds__(256) void k_mm(const float* __restrict__ agg, const float* __restrict__ W,
                                            const float* __restrict__ bias, const float* __restrict__ g,
                                            const float* __restrict__ be,
                                            float* __restrict__ h, float* __restrict__ hsum) {
  __shared__ float red1[8][32], red2[8][32];
  __shared__ float sc[32], sh[32];
  int t = threadIdx.x, c0 = blockIdx.x * 32;
  int c = t & 31, gq = t >> 5;
  float o[16];
  float bv = bias[c0 + c];
  #pragma unroll
  for (int j = 0; j < 16; j++) o[j] = bv;
  for (int k = 0; k < 128; k++) {
    float w = W[k * 128 + c0 + c];
    #pragma unroll
    for (int j = 0; j < 16; j++) o[j] += agg[(gq * 16 + j) * 128 + k] * w;
  }
  float s1 = 0.f, s2 = 0.f;
  #pragma unroll
  for (int j = 0; j < 16; j++) { s1 += o[j]; s2 += o[j] * o[j]; }
  red1[gq][c] = s1; red2[gq][c] = s2;
  __syncthreads();
  if (t < 32) {
    float a1 = 0.f, a2 = 0.f;
    #pragma unroll
    for (int q = 0; q < 8; q++) { a1 += red1[q][t]; a2 += red2[q][t]; }
    float mu = a1 * (1.f / 128.f), var = a2 * (1.f / 128.f) - mu * mu;
    float a = g[c0 + t] * rsqrtf(var + 1e-5f);
    sc[t] = a; sh[t] = be[c0 + t] - a * mu;
  }
  __syncthreads();
  #pragma unroll
  for (int j = 0; j < 16; j++) {
    int idx = (gq * 16 + j) * 128 + c0 + c;
    float hn = fmaxf(sc[c] * o[j] + sh[c], 0.f);
    float hnew = hn + h[idx];
    h[idx] = hnew;
    hsum[idx] += hnew;
  }
}

__global__ __launch_bounds__(512) void k_cls(const float* __restrict__ hsum,
    const float* __restrict__ c1W, const float* __restrict__ c1b,
    const float* __restrict__ lng, const float* __restrict__ lnbe,
    const float* __restrict__ c2W, const float* __restrict__ c2b,
    const float* __restrict__ rloss, float* __restrict__ out) {
  __shared__ float w[8192];
  __shared__ float red[128][8];
  int t = threadIdx.x;
  for (int idx = t; idx < 8192; idx += 512) w[idx] = c1W[idx];
  __syncthreads();
  int r = t >> 2, cg = t & 3;
  float z[16];
  #pragma unroll
  for (int j = 0; j < 16; j++) z[j] = c1b[cg * 16 + j];
  for (int k = 0; k < 128; k++) {
    float hv = hsum[r * 128 + k] * 0.25f;     // h = h_sum / 4
    #pragma unroll
    for (int j = 0; j < 16; j++) z[j] += hv * w[k * 64 + cg * 16 + j];
  }
  float s1 = 0.f, s2 = 0.f;
  #pragma unroll
  for (int j = 0; j < 16; j++) { s1 += z[j]; s2 += z[j] * z[j]; }
  red[r][cg] = s1; red[r][4 + cg] = s2;
  __syncthreads();
  float mu = (red[r][0] + red[r][1] + red[r][2] + red[r][3]) * (1.f / 64.f);
  float var = (red[r][4] + red[r][5] + red[r][6] + red[r][7]) * (1.f / 64.f) - mu * mu;
  float rs = rsqrtf(var + 1e-5f);
  float l0 = 0.f, l1 = 0.f;
  #pragma unroll
  for (int j = 0; j < 16; j++) {
    int cc = cg * 16 + j;
    float zn = fmaxf(lng[cc] * (z[j] - mu) * rs + lnbe[cc], 0.f);
    l0 += zn * c2W[cc * 2];
    l1 += zn * c2W[cc * 2 + 1];
  }
  __syncthreads();
  red[r][cg] = l0; red[r][4 + cg] = l1;
  __syncthreads();
  if (cg == 0) {
    out[r * 2]     = red[r][0] + red[r][1] + red[r][2] + red[r][3] + c2b[0];
    out[r * 2 + 1] = red[r][4] + red[r][5] + red[r][6] + red[r][7] + c2b[1];
  }
  if (t == 0) out[256] = rloss[0];
}

// ---------------------------------------------------------------------------
extern "C" void kernel_launch(void* const* d_in, const int* in_sizes, int n_in,
                              void* d_out, int out_size, void* d_ws, size_t ws_size,
                              hipStream_t stream) {
  (void)in_sizes; (void)n_in; (void)out_size; (void)ws_size;
  const float* plane_feat  = (const float*)d_in[0];
  const int*   plane_src   = (const int*)d_in[1];
  const int*   plane_dst   = (const int*)d_in[2];
  const int*   patient_src = (const int*)d_in[3];
  const int*   patient_dst = (const int*)d_in[4];
  const float* orig        = (const float*)d_in[5];
  const int*   mask        = (const int*)d_in[6];
  const float* W1   = (const float*)d_in[7];
  const float* al1  = (const float*)d_in[8];
  const float* ar1  = (const float*)d_in[9];
  const float* res1 = (const float*)d_in[10];
  const float* b1   = (const float*)d_in[11];
  const float* g1   = (const float*)d_in[12];
  const float* be1  = (const float*)d_in[13];
  const float* W2   = (const float*)d_in[14];
  const float* al2  = (const float*)d_in[15];
  const float* ar2  = (const float*)d_in[16];
  const float* res2 = (const float*)d_in[17];
  const float* g2   = (const float*)d_in[19];
  const float* be2  = (const float*)d_in[20];
  const float* dW1  = (const float*)d_in[21];
  const float* dg   = (const float*)d_in[23];
  const float* dbe  = (const float*)d_in[24];
  const float* dW2  = (const float*)d_in[25];
  const float* db2  = (const float*)d_in[26];
  const float* ftW  = (const float*)d_in[27];
  const float* ftb  = (const float*)d_in[28];
  const float* ftg  = (const float*)d_in[29];
  const float* ftbe = (const float*)d_in[30];
  const float* gcW  = (const float*)d_in[31];
  const float* gcb  = (const float*)d_in[32];
  const float* gbng = (const float*)d_in[33];
  const float* gbnbe= (const float*)d_in[34];
  const float* c1W  = (const float*)d_in[35];
  const float* c1b  = (const float*)d_in[36];
  const float* lng  = (const float*)d_in[37];
  const float* lnbe = (const float*)d_in[38];
  const float* c2W  = (const float*)d_in[39];
  const float* c2b  = (const float*)d_in[40];

  float* ws   = (float*)d_ws;
  float* rep  = ws;                       // [128][512]
  float* u0   = ws + 65536;               // [128][128]
  float* h    = ws + 81920;               // [128][128]
  float* hsum = ws + 98304;               // [128][128]
  float* agg  = ws + 114688;              // [128][128]
  float* deg  = ws + 131072;              // [256]
  float* rl   = ws + 131328;              // [1]
  float* outp = (float*)d_out;

  hipMemsetAsync(rl, 0, sizeof(float), stream);
  plane_enc<<<2048, 256, 0, stream>>>(plane_feat, plane_src, plane_dst,
      W1, al1, ar1, res1, b1, g1, be1, W2, al2, ar2, res2, g2, be2,
      dW1, dg, dbe, dW2, db2, rep, rl);
  k_b1<<<128, 128, 0, stream>>>(orig, rep, ftW, ftb, u0);
  k_b2<<<1, 1024, 0, stream>>>(u0, ftg, ftbe, patient_src, patient_dst, h, hsum, deg);
  for (int i = 0; i < 3; i++) {
    k_agg<<<4, 256, 0, stream>>>(h, mask, patient_src, patient_dst, deg, agg);
    k_mm<<<4, 256, 0, stream>>>(agg, gcW + i * 16384, gcb + i * 128,
                                gbng + i * 128, gbnbe + i * 128, h, hsum);
  }
  k_cls<<<1, 512, 0, stream>>>(hsum, c1W, c1b, lng, lnbe, c2W, c2b, rl, outp);
}

// Round 3
// 401.328 us; speedup vs baseline: 1.9939x; 1.2842x over previous
//
#include <hip/hip_runtime.h>

#define B_    128
#define P_    16
#define NP_   256
#define EP_   1280
#define EPG_  2048
#define ODIM_ 256
#define NH_   128

typedef __attribute__((ext_vector_type(8))) short s8_t;
typedef __attribute__((ext_vector_type(4))) float f4_t;

__device__ __forceinline__ unsigned short f2b(float x) {
  unsigned u = __builtin_bit_cast(unsigned, x);
  u = (u + 0x7fffu + ((u >> 16) & 1u)) >> 16;
  return (unsigned short)u;
}
__device__ __forceinline__ float b2f(short x) {
  unsigned u = ((unsigned)(unsigned short)x) << 16;
  return __builtin_bit_cast(float, u);
}

// ---------------------------------------------------------------------------
// Stage A: one block (256 thr) per plane graph (2048).
// z2 holds only the z-half [256][32+8pad] bf16; res-half stays in C-frag regs
// through aggregation, then round-trips through z2 (saves ~18 KB LDS ->
// 3 blocks/CU instead of 2).
// ---------------------------------------------------------------------------
struct SmemA {
  float f[256];
  float S0a[256], S1a[256];
  float el2[256], er2[256];
  float abg0[128], abg1[128], abg2[128];
  float al2v[32], ar2v[32];
  __align__(16) unsigned short wT[64 * 136];   // W2|res2 ^T bf16; later dW1T [128][40]
  __align__(16) unsigned short z2[256 * 40];   // bf16 [256][32+8pad]
  int cnt[256]; int wtot[4];
  unsigned short esrc[1280];
  float redf[512];
  float scA[32], shA[32];
  float dscA[64], dshA[64];
  float dW2v[128];
  float r8[4][8]; float stat[8]; float wA[2], wB[2];
  float rlacc;
};

__global__ __launch_bounds__(256, 3) void plane_enc(
    const float* __restrict__ feat, const int* __restrict__ esrcg, const int* __restrict__ edstg,
    const float* __restrict__ W1, const float* __restrict__ al1, const float* __restrict__ ar1,
    const float* __restrict__ res1, const float* __restrict__ b1, const float* __restrict__ g1,
    const float* __restrict__ be1,
    const float* __restrict__ W2, const float* __restrict__ al2, const float* __restrict__ ar2,
    const float* __restrict__ res2, const float* __restrict__ g2, const float* __restrict__ be2,
    const float* __restrict__ dW1, const float* __restrict__ dg, const float* __restrict__ dbe,
    const float* __restrict__ dW2, const float* __restrict__ db2,
    float* __restrict__ rep_out, float* __restrict__ rloss_out)
{
  __shared__ SmemA s;
  const int g = blockIdx.x;
  const int p = g & 15;
  const int t = threadIdx.x;
  const int lane = t & 63, wv = t >> 6;
  const int l15 = lane & 15, quad = lane >> 4;

  s.f[t] = feat[g * NP_ + t];
  if (t < 32) { s.al2v[t] = al2[p * 32 + t]; s.ar2v[t] = ar2[p * 32 + t]; }
  if (t == 0) s.rlacc = 0.f;
  s.cnt[t] = 0;
  __syncthreads();

  // ---- counting-sort edges by dst ------------------------------------------
  const int* gs = esrcg + g * EP_;
  const int* gd = edstg + g * EP_;
  for (int k = t; k < EP_; k += 256) atomicAdd(&s.cnt[gd[k]], 1);
  __syncthreads();
  int v = s.cnt[t];
  int incl = v;
  #pragma unroll
  for (int off = 1; off < 64; off <<= 1) {
    int n = __shfl_up(incl, off, 64);
    if (lane >= off) incl += n;
  }
  if (lane == 63) s.wtot[wv] = incl;
  __syncthreads();
  int woff = 0;
  for (int w = 0; w < wv; w++) woff += s.wtot[w];
  const int myStart = woff + incl - v;
  const int myDeg = v;
  __syncthreads();
  s.cnt[t] = myStart;
  __syncthreads();
  for (int k = t; k < EP_; k += 256) {
    int d = gd[k];
    int pos = atomicAdd(&s.cnt[d], 1);
    s.esrc[pos] = (unsigned short)gs[k];
  }
  // stage WcT = [W2|res2]^T bf16
  {
    const float* W2g = W2 + p * 4096;
    const float* Rg  = res2 + p * 4096;
    for (int q = 0; q < 16; q++) {
      int idx = t + 256 * q;                 // idx = k*32 + n
      int k = idx >> 5, n = idx & 31;
      s.wT[n * 136 + k]        = f2b(W2g[idx]);
      s.wT[(n + 32) * 136 + k] = f2b(Rg[idx]);
    }
  }
  if (t < 128) {
    float w1v = W1[p * 128 + t];
    s.el2[t] = w1v * al1[p * 128 + t];
    s.er2[t] = w1v * ar1[p * 128 + t];
  }
  __syncthreads();
  if (t < 2) {
    float a = 0.f, bq = 0.f;
    for (int d2 = 0; d2 < 64; d2++) { a += s.el2[t * 64 + d2]; bq += s.er2[t * 64 + d2]; }
    s.wA[t] = a; s.wB[t] = bq;
  }
  __syncthreads();

  // ---- layer-1 rank-1 edge softmax -----------------------------------------
  const float fi = s.f[t];
  float S0, S1;
  {
    const float wa0 = s.wA[0], wb0 = s.wB[0], wa1 = s.wA[1], wb1 = s.wB[1];
    float m0 = -1e30f, m1 = -1e30f;
    for (int j = 0; j < myDeg; j++) {
      float fs = s.f[s.esrc[myStart + j]];
      float e0 = wa0 * fs + wb0 * fi; e0 = e0 > 0.f ? e0 : 0.2f * e0;
      float e1 = wa1 * fs + wb1 * fi; e1 = e1 > 0.f ? e1 : 0.2f * e1;
      m0 = fmaxf(m0, e0); m1 = fmaxf(m1, e1);
    }
    float ss0 = 0.f, ss1 = 0.f, U0 = 0.f, U1 = 0.f;
    for (int j = 0; j < myDeg; j++) {
      float fs = s.f[s.esrc[myStart + j]];
      float e0 = wa0 * fs + wb0 * fi; e0 = e0 > 0.f ? e0 : 0.2f * e0;
      float e1 = wa1 * fs + wb1 * fi; e1 = e1 > 0.f ? e1 : 0.2f * e1;
      float x0 = __expf(e0 - m0), x1 = __expf(e1 - m1);
      ss0 += x0; U0 += x0 * fs;
      ss1 += x1; U1 += x1 * fs;
    }
    S0 = U0 / (ss0 + 1e-9f);
    S1 = U1 / (ss1 + 1e-9f);
    s.S0a[t] = S0; s.S1a[t] = S1;
  }

  // ---- layer-1 BN via scalar moments ---------------------------------------
  {
    float vals[8] = {fi, fi * fi, S0, S0 * S0, S0 * fi, S1, S1 * S1, S1 * fi};
    #pragma unroll
    for (int d2 = 32; d2 > 0; d2 >>= 1) {
      #pragma unroll
      for (int q = 0; q < 8; q++) vals[q] += __shfl_down(vals[q], d2, 64);
    }
    if (lane == 0) {
      #pragma unroll
      for (int q = 0; q < 8; q++) s.r8[wv][q] = vals[q];
    }
  }
  __syncthreads();
  if (t < 8) s.stat[t] = (s.r8[0][t] + s.r8[1][t] + s.r8[2][t] + s.r8[3][t]) * (1.f / 256.f);
  __syncthreads();
  if (t < 128) {
    float mf = s.stat[0], ef2 = s.stat[1];
    int hh = t >> 6;
    float mS = s.stat[2 + 3 * hh], eS2 = s.stat[3 + 3 * hh], eSf = s.stat[4 + 3 * hh];
    float varS = eS2 - mS * mS, varf = ef2 - mf * mf, cov = eSf - mS * mf;
    float Wv = W1[p * 128 + t], Rv = res1[p * 128 + t], Bv = b1[p * 128 + t];
    float mu  = Wv * mS + Rv * mf + Bv;
    float var = Wv * Wv * varS + Rv * Rv * varf + 2.f * Wv * Rv * cov;
    float gn  = g1[p * 128 + t] * rsqrtf(var + 1e-5f);
    s.abg0[t] = gn * Wv;
    s.abg1[t] = gn * Rv;
    s.abg2[t] = gn * (Bv - mu) + be1[p * 128 + t];
  }
  __syncthreads();

  // ---- matmul1 (MFMA): [z|res][256x64] = h1 @ [W2|res2] --------------------
  float resv[32];
  {
    f4_t accum[4][4];
    #pragma unroll
    for (int i = 0; i < 4; i++)
      #pragma unroll
      for (int nt = 0; nt < 4; nt++) accum[i][nt] = (f4_t){0.f, 0.f, 0.f, 0.f};

    float fm[4], s0m[4], s1m[4];
    #pragma unroll
    for (int i = 0; i < 4; i++) {
      int m = (wv * 4 + i) * 16 + l15;
      fm[i] = s.f[m]; s0m[i] = s.S0a[m]; s1m[i] = s.S1a[m];
    }
    #pragma unroll
    for (int kt = 0; kt < 4; kt++) {
      int cbase = kt * 32 + quad * 8;
      float a0[8], a1[8], a2[8];
      #pragma unroll
      for (int j = 0; j < 8; j++) {
        a0[j] = s.abg0[cbase + j]; a1[j] = s.abg1[cbase + j]; a2[j] = s.abg2[cbase + j];
      }
      s8_t afr[4];
      #pragma unroll
      for (int i = 0; i < 4; i++) {
        float Sm = (kt < 2) ? s0m[i] : s1m[i];
        union { s8_t v; unsigned short u[8]; } fu;
        #pragma unroll
        for (int j = 0; j < 8; j++) {
          float h = fmaxf(fmaf(a0[j], Sm, fmaf(a1[j], fm[i], a2[j])), 0.f);
          fu.u[j] = f2b(h);
        }
        afr[i] = fu.v;
      }
      s8_t bfr[4];
      #pragma unroll
      for (int nt = 0; nt < 4; nt++)
        bfr[nt] = *(const s8_t*)&s.wT[(nt * 16 + l15) * 136 + cbase];
      #pragma unroll
      for (int i = 0; i < 4; i++)
        #pragma unroll
        for (int nt = 0; nt < 4; nt++)
          accum[i][nt] = __builtin_amdgcn_mfma_f32_16x16x32_bf16(afr[i], bfr[nt], accum[i][nt], 0, 0, 0);
    }
    // write z-half (cols 0..31); keep res-half in regs
    #pragma unroll
    for (int i = 0; i < 4; i++) {
      int mBase = (wv * 4 + i) * 16 + quad * 4;
      #pragma unroll
      for (int nt = 0; nt < 2; nt++) {
        int col = nt * 16 + l15;
        #pragma unroll
        for (int r = 0; r < 4; r++)
          s.z2[(mBase + r) * 40 + col] = f2b(accum[i][nt][r]);
      }
      #pragma unroll
      for (int h2 = 0; h2 < 2; h2++)
        #pragma unroll
        for (int r = 0; r < 4; r++)
          resv[(i * 2 + h2) * 4 + r] = accum[i][2 + h2][r];
    }
  }
  __syncthreads();

  // ---- attn logits; stage dW1T ---------------------------------------------
  {
    const s8_t* zr = (const s8_t*)&s.z2[t * 40];
    float el = 0.f, er = 0.f;
    #pragma unroll
    for (int q = 0; q < 4; q++) {
      s8_t vz = zr[q];
      #pragma unroll
      for (int j = 0; j < 8; j++) {
        float zv = b2f(vz[j]);
        el += zv * s.al2v[q * 8 + j];
        er += zv * s.ar2v[q * 8 + j];
      }
    }
    s.el2[t] = el; s.er2[t] = er;
  }
  {
    const float* Dg = dW1 + p * 4096;          // [32][128]
    for (int q = 0; q < 16; q++) {
      int idx = t + 256 * q;
      int k = idx >> 7, n = idx & 127;
      s.wT[n * 40 + k] = f2b(Dg[idx]);
    }
    if (t < 128) s.dW2v[t] = dW2[p * 128 + t];
  }
  const float db2v = db2[p];
  __syncthreads();

  // ---- layer-2 edge softmax + aggregate ------------------------------------
  float hrow[32];
  {
    const float eri = s.er2[t];
    float m = -1e30f;
    for (int j = 0; j < myDeg; j++) {
      float e = s.el2[s.esrc[myStart + j]] + eri;
      e = e > 0.f ? e : 0.2f * e;
      m = fmaxf(m, e);
    }
    float ss = 0.f;
    #pragma unroll
    for (int d2 = 0; d2 < 32; d2++) hrow[d2] = 0.f;
    for (int j = 0; j < myDeg; j++) {
      int sj = s.esrc[myStart + j];
      float e = s.el2[sj] + eri;
      e = e > 0.f ? e : 0.2f * e;
      float x = __expf(e - m);
      ss += x;
      const s8_t* zr = (const s8_t*)&s.z2[sj * 40];
      #pragma unroll
      for (int q = 0; q < 4; q++) {
        s8_t vz = zr[q];
        #pragma unroll
        for (int jj = 0; jj < 8; jj++) hrow[q * 8 + jj] += x * b2f(vz[jj]);
      }
    }
    float inv = 1.f / (ss + 1e-9f);
    #pragma unroll
    for (int d2 = 0; d2 < 32; d2++) hrow[d2] *= inv;
  }
  __syncthreads();                // all reads of z done
  // res-half exchange through z2
  #pragma unroll
  for (int i = 0; i < 4; i++) {
    int mBase = (wv * 4 + i) * 16 + quad * 4;
    #pragma unroll
    for (int h2 = 0; h2 < 2; h2++) {
      int col = h2 * 16 + l15;
      #pragma unroll
      for (int r = 0; r < 4; r++)
        s.z2[(mBase + r) * 40 + col] = f2b(resv[(i * 2 + h2) * 4 + r]);
    }
  }
  __syncthreads();
  {
    const s8_t* zr = (const s8_t*)&s.z2[t * 40];
    #pragma unroll
    for (int q = 0; q < 4; q++) {
      s8_t vz = zr[q];
      #pragma unroll
      for (int jj = 0; jj < 8; jj++) hrow[q * 8 + jj] += b2f(vz[jj]);
    }
  }
  #pragma unroll
  for (int d2 = 0; d2 < 32; d2++) s.z2[t * 40 + d2] = f2b(hrow[d2]);  // pre-BN
  __syncthreads();

  // ---- layer-2 BN + relu + rep ---------------------------------------------
  {
    int c = t & 31, gq = t >> 5;
    float s1 = 0.f, s2 = 0.f;
    for (int j = 0; j < 32; j++) {
      float vz = b2f((short)s.z2[(gq * 32 + j) * 40 + c]);
      s1 += vz; s2 += vz * vz;
    }
    s.redf[t] = s1; s.redf[256 + t] = s2;
  }
  __syncthreads();
  if (t < 32) {
    float s1 = 0.f, s2 = 0.f;
    #pragma unroll
    for (int q = 0; q < 8; q++) { s1 += s.redf[q * 32 + t]; s2 += s.redf[256 + q * 32 + t]; }
    float mu = s1 * (1.f / 256.f);
    float var = s2 * (1.f / 256.f) - mu * mu;
    float a = g2[p * 32 + t] * rsqrtf(var + 1e-5f);
    s.scA[t] = a; s.shA[t] = be2[p * 32 + t] - a * mu;
  }
  __syncthreads();
  {
    int c = t & 31, gq = t >> 5;
    float a = s.scA[c], bb = s.shA[c];
    float s1 = 0.f;
    for (int j = 0; j < 32; j++) {
      int ad = (gq * 32 + j) * 40 + c;
      float vz = b2f((short)s.z2[ad]);
      float hv = fmaxf(a * vz + bb, 0.f);
      s.z2[ad] = f2b(hv);
      s1 += hv;
    }
    s.redf[t] = s1;
  }
  __syncthreads();
  if (t < 32) {
    float s1 = 0.f;
    #pragma unroll
    for (int q = 0; q < 8; q++) s1 += s.redf[q * 32 + t];
    rep_out[g * 32 + t] = s1 * (1.f / 256.f);
  }
  __syncthreads();

  // ---- matmul2 (MFMA) + decoder BN + recon ---------------------------------
  {
    s8_t afr2[4];
    #pragma unroll
    for (int i = 0; i < 4; i++)
      afr2[i] = *(const s8_t*)&s.z2[((wv * 4 + i) * 16 + l15) * 40 + quad * 8];
    float rAcc[4][4];
    #pragma unroll
    for (int i = 0; i < 4; i++)
      #pragma unroll
      for (int r = 0; r < 4; r++) rAcc[i][r] = 0.f;

    for (int half = 0; half < 2; half++) {
      __syncthreads();
      s.redf[t] = 0.f; s.redf[256 + t] = 0.f;
      __syncthreads();
      f4_t acc2[4][4];
      #pragma unroll
      for (int i = 0; i < 4; i++)
        #pragma unroll
        for (int nt = 0; nt < 4; nt++) acc2[i][nt] = (f4_t){0.f, 0.f, 0.f, 0.f};
      s8_t bfr[4];
      #pragma unroll
      for (int nt = 0; nt < 4; nt++)
        bfr[nt] = *(const s8_t*)&s.wT[(half * 64 + nt * 16 + l15) * 40 + quad * 8];
      #pragma unroll
      for (int i = 0; i < 4; i++)
        #pragma unroll
        for (int nt = 0; nt < 4; nt++)
          acc2[i][nt] = __builtin_amdgcn_mfma_f32_16x16x32_bf16(afr2[i], bfr[nt], acc2[i][nt], 0, 0, 0);
      #pragma unroll
      for (int nt = 0; nt < 4; nt++) {
        float s1 = 0.f, s2 = 0.f;
        #pragma unroll
        for (int i = 0; i < 4; i++)
          #pragma unroll
          for (int r = 0; r < 4; r++) { float vv = acc2[i][nt][r]; s1 += vv; s2 += vv * vv; }
        atomicAdd(&s.redf[nt * 16 + l15], s1);
        atomicAdd(&s.redf[256 + nt * 16 + l15], s2);
      }
      __syncthreads();
      if (t < 64) {
        int col = half * 64 + t;
        float mu = s.redf[t] * (1.f / 256.f);
        float var = s.redf[256 + t] * (1.f / 256.f) - mu * mu;
        float a = dg[p * 128 + col] * rsqrtf(var + 1e-5f);
        s.dscA[t] = a; s.dshA[t] = dbe[p * 128 + col] - a * mu;
      }
      __syncthreads();
      #pragma unroll
      for (int nt = 0; nt < 4; nt++) {
        int cl = nt * 16 + l15;
        float a = s.dscA[cl], bb = s.dshA[cl], w2 = s.dW2v[half * 64 + cl];
        #pragma unroll
        for (int i = 0; i < 4; i++)
          #pragma unroll
          for (int r = 0; r < 4; r++) {
            float dv = fmaxf(a * acc2[i][nt][r] + bb, 0.f);
            rAcc[i][r] += dv * w2;
          }
      }
    }
    #pragma unroll
    for (int off = 1; off < 16; off <<= 1)
      #pragma unroll
      for (int i = 0; i < 4; i++)
        #pragma unroll
        for (int r = 0; r < 4; r++) rAcc[i][r] += __shfl_xor(rAcc[i][r], off, 64);
    if (l15 == 0) {
      float sq = 0.f;
      #pragma unroll
      for (int i = 0; i < 4; i++)
        #pragma unroll
        for (int r = 0; r < 4; r++) {
          int m = (wv * 4 + i) * 16 + quad * 4 + r;
          float diff = rAcc[i][r] + db2v - s.f[m];
          sq += diff * diff;
        }
      atomicAdd(&s.rlacc, sq);
    }
  }
  __syncthreads();
  if (t == 0) atomicAdd(rloss_out, s.rlacc * (1.f / (256.f * 2048.f)));
}

// ---------------------------------------------------------------------------
// ft matmul: u0 = [orig|rep] @ ftW + ftb   (128 blocks, parallel-wide)
// ---------------------------------------------------------------------------
__global__ __launch_bounds__(128) void k_b1(const float* __restrict__ orig, const float* __restrict__ rep,
                                            const float* __restrict__ ftW, const float* __restrict__ ftb,
                                            float* __restrict__ u0) {
  __shared__ float x[768];
  int b = blockIdx.x, t = threadIdx.x;
  for (int j = t; j < 256; j += 128) x[j] = orig[b * 256 + j];
  for (int j = t; j < 512; j += 128) x[256 + j] = rep[b * 512 + j];
  __syncthreads();
  float a = ftb[t];
  #pragma unroll 8
  for (int k = 0; k < 768; k++) a += x[k] * ftW[k * 128 + t];
  u0[b * 128 + t] = a;
}

// ---------------------------------------------------------------------------
// Fused patient-level stage: BN(ft) + 3x(masked GC + BN + relu + residual)
// + classifier. ONE block, 1024 threads, everything in LDS, matmuls on MFMA.
// gc_b and ft_b biases cancel through BN; c1_b does NOT (LN over features).
// ---------------------------------------------------------------------------
struct SmemB {
  float hF[128 * 129];                       // h, fp32 (stride 129: conflict-free gather)
  __align__(16) unsigned short aggB[128 * 136];  // bf16 A (agg; later hsum/4)
  union {
    __align__(16) unsigned short wTb[128 * 136]; // bf16 B^T (gcW / c1W)
    float zF[128 * 68];                          // cls pre-LN (exact same bytes)
  } u;
  float redA[8 * 128], redB[8 * 128];
  float facs[128], facd[128];
  float scB[128], shB[128];
  int co[128], ci[128], startB[128], fillB[128];
  unsigned short esrcB[2048];
};

__global__ __launch_bounds__(1024) void k_patient(
    const float* __restrict__ u0, const float* __restrict__ ftg, const float* __restrict__ ftbe,
    const int* __restrict__ ps, const int* __restrict__ pd, const int* __restrict__ mask,
    const float* __restrict__ gcW, const float* __restrict__ gbng, const float* __restrict__ gbnbe,
    const float* __restrict__ c1W, const float* __restrict__ c1b,
    const float* __restrict__ lng, const float* __restrict__ lnbe,
    const float* __restrict__ c2W, const float* __restrict__ c2b,
    const float* __restrict__ rl, float* __restrict__ out)
{
  __shared__ SmemB s;
  const int t = threadIdx.x;
  const int w = t >> 6, lane = t & 63;
  const int l15 = lane & 15, quad = lane >> 4;
  const int mb = w & 7, nb = (w >> 3) * 64;
  const int c = t & 127, gq = t >> 7;

  if (t < 128) { s.co[t] = 0; s.ci[t] = 0; }
  __syncthreads();
  for (int e = t; e < EPG_; e += 1024) { atomicAdd(&s.co[ps[e]], 1); atomicAdd(&s.ci[pd[e]], 1); }
  __syncthreads();
  if (t == 0) {
    int run = 0;
    for (int i = 0; i < 128; i++) { s.startB[i] = run; run += s.ci[i]; }
  }
  if (t < 128) {
    float mk = (float)mask[t];
    int da = s.co[t] > 1 ? s.co[t] : 1;
    int db = s.ci[t] > 1 ? s.ci[t] : 1;
    s.facs[t] = mk * rsqrtf((float)da);
    s.facd[t] = mk * rsqrtf((float)db);
  }
  __syncthreads();
  if (t < 128) s.fillB[t] = s.startB[t];
  __syncthreads();
  for (int e = t; e < EPG_; e += 1024) {
    int pos = atomicAdd(&s.fillB[pd[e]], 1);
    s.esrcB[pos] = (unsigned short)ps[e];
  }

  // ---- BN(u0) + relu -> hF -------------------------------------------------
  {
    float s1 = 0.f, s2 = 0.f;
    #pragma unroll
    for (int j = 0; j < 16; j++) { float v = u0[(gq * 16 + j) * 128 + c]; s1 += v; s2 += v * v; }
    s.redA[gq * 128 + c] = s1; s.redB[gq * 128 + c] = s2;
  }
  __syncthreads();
  if (t < 128) {
    float a1 = 0.f, a2 = 0.f;
    #pragma unroll
    for (int q = 0; q < 8; q++) { a1 += s.redA[q * 128 + t]; a2 += s.redB[q * 128 + t]; }
    float mu = a1 * (1.f / 128.f), var = a2 * (1.f / 128.f) - mu * mu;
    float a = ftg[t] * rsqrtf(var + 1e-5f);
    s.scB[t] = a; s.shB[t] = ftbe[t] - a * mu;
  }
  __syncthreads();
  {
    float a = s.scB[c], bb = s.shB[c];
    #pragma unroll
    for (int j = 0; j < 16; j++) {
      int row = gq * 16 + j;
      s.hF[row * 129 + c] = fmaxf(a * u0[row * 128 + c] + bb, 0.f);
    }
  }
  __syncthreads();

  // hsum in regs with MFMA-C ownership: v = nt*4+r -> (row=mb*16+quad*4+r, col=nb+nt*16+l15)
  float hsumR[16];
  #pragma unroll
  for (int nt = 0; nt < 4; nt++)
    #pragma unroll
    for (int r = 0; r < 4; r++)
      hsumR[nt * 4 + r] = s.hF[(mb * 16 + quad * 4 + r) * 129 + nb + nt * 16 + l15];

  // ---- 3 GC layers ---------------------------------------------------------
  for (int layer = 0; layer < 3; layer++) {
    // stage W^T bf16
    const float* Wg = gcW + layer * 16384;
    #pragma unroll
    for (int q = 0; q < 16; q++) {
      int idx = t + 1024 * q;
      int n = idx & 127, k = idx >> 7;
      s.u.wTb[n * 136 + k] = f2b(Wg[k * 128 + n]);
    }
    // gather agg (dst-sorted, no atomics)
    #pragma unroll 1
    for (int j = 0; j < 16; j++) {
      int row = gq * 16 + j;
      int st = s.startB[row], de = s.ci[row];
      float acc = 0.f;
      for (int e = 0; e < de; e++) {
        int sN = s.esrcB[st + e];
        acc += s.hF[sN * 129 + c] * s.facs[sN];
      }
      s.aggB[row * 136 + c] = f2b(acc * s.facd[row]);
    }
    __syncthreads();
    // MFMA: o[128x128] = agg @ W  (wave w: rows mb*16.., cols nb..nb+63)
    f4_t acc[4];
    #pragma unroll
    for (int nt = 0; nt < 4; nt++) acc[nt] = (f4_t){0.f, 0.f, 0.f, 0.f};
    #pragma unroll
    for (int ks = 0; ks < 4; ks++) {
      s8_t afr = *(const s8_t*)&s.aggB[(mb * 16 + l15) * 136 + ks * 32 + quad * 8];
      #pragma unroll
      for (int nt = 0; nt < 4; nt++) {
        s8_t bfr = *(const s8_t*)&s.u.wTb[(nb + nt * 16 + l15) * 136 + ks * 32 + quad * 8];
        acc[nt] = __builtin_amdgcn_mfma_f32_16x16x32_bf16(afr, bfr, acc[nt], 0, 0, 0);
      }
    }
    // BN stats: quad-reduce then per-(mb) partials, no atomics
    #pragma unroll
    for (int nt = 0; nt < 4; nt++) {
      float s1 = acc[nt][0] + acc[nt][1] + acc[nt][2] + acc[nt][3];
      float s2 = acc[nt][0]*acc[nt][0] + acc[nt][1]*acc[nt][1] + acc[nt][2]*acc[nt][2] + acc[nt][3]*acc[nt][3];
      s1 += __shfl_xor(s1, 16, 64); s1 += __shfl_xor(s1, 32, 64);
      s2 += __shfl_xor(s2, 16, 64); s2 += __shfl_xor(s2, 32, 64);
      if (quad == 0) {
        s.redA[mb * 128 + nb + nt * 16 + l15] = s1;
        s.redB[mb * 128 + nb + nt * 16 + l15] = s2;
      }
    }
    __syncthreads();
    if (t < 128) {
      float a1 = 0.f, a2 = 0.f;
      #pragma unroll
      for (int q = 0; q < 8; q++) { a1 += s.redA[q * 128 + t]; a2 += s.redB[q * 128 + t]; }
      float mu = a1 * (1.f / 128.f), var = a2 * (1.f / 128.f) - mu * mu;
      float a = gbng[layer * 128 + t] * rsqrtf(var + 1e-5f);
      s.scB[t] = a; s.shB[t] = gbnbe[layer * 128 + t] - a * mu;
    }
    __syncthreads();
    // h update + hsum accumulate
    #pragma unroll
    for (int nt = 0; nt < 4; nt++) {
      int col = nb + nt * 16 + l15;
      float a = s.scB[col], bb = s.shB[col];
      #pragma unroll
      for (int r = 0; r < 4; r++) {
        int row = mb * 16 + quad * 4 + r;
        float hn = fmaxf(a * acc[nt][r] + bb, 0.f);
        float hnew = hn + s.hF[row * 129 + col];
        s.hF[row * 129 + col] = hnew;
        hsumR[nt * 4 + r] += hnew;
      }
    }
    __syncthreads();
  }

  // ---- classifier ----------------------------------------------------------
  // A = hsum/4 bf16; B = c1W^T
  #pragma unroll
  for (int nt = 0; nt < 4; nt++)
    #pragma unroll
    for (int r = 0; r < 4; r++)
      s.aggB[(mb * 16 + quad * 4 + r) * 136 + nb + nt * 16 + l15] = f2b(hsumR[nt * 4 + r] * 0.25f);
  #pragma unroll
  for (int q = 0; q < 8; q++) {
    int idx = t + 1024 * q;
    int n = idx & 63, k = idx >> 6;
    s.u.wTb[n * 136 + k] = f2b(c1W[k * 64 + n]);
  }
  __syncthreads();
  {
    const int nb2 = (w >> 3) * 32;
    f4_t acc[2];
    #pragma unroll
    for (int nt = 0; nt < 2; nt++) acc[nt] = (f4_t){0.f, 0.f, 0.f, 0.f};
    #pragma unroll
    for (int ks = 0; ks < 4; ks++) {
      s8_t afr = *(const s8_t*)&s.aggB[(mb * 16 + l15) * 136 + ks * 32 + quad * 8];
      #pragma unroll
      for (int nt = 0; nt < 2; nt++) {
        s8_t bfr = *(const s8_t*)&s.u.wTb[(nb2 + nt * 16 + l15) * 136 + ks * 32 + quad * 8];
        acc[nt] = __builtin_amdgcn_mfma_f32_16x16x32_bf16(afr, bfr, acc[nt], 0, 0, 0);
      }
    }
    __syncthreads();   // all wTb reads done before zF (union) writes
    #pragma unroll
    for (int nt = 0; nt < 2; nt++) {
      int col = nb2 + nt * 16 + l15;
      #pragma unroll
      for (int r = 0; r < 4; r++)
        s.u.zF[(mb * 16 + quad * 4 + r) * 68 + col] = acc[nt][r] + c1b[col];
    }
  }
  __syncthreads();
  if (t < 128) {
    float s1 = 0.f, s2 = 0.f;
    #pragma unroll
    for (int j = 0; j < 64; j++) { float zv = s.u.zF[t * 68 + j]; s1 += zv; s2 += zv * zv; }
    float mu = s1 * (1.f / 64.f);
    float var = s2 * (1.f / 64.f) - mu * mu;
    float rs = rsqrtf(var + 1e-5f);
    float l0 = 0.f, l1 = 0.f;
    #pragma unroll
    for (int j = 0; j < 64; j++) {
      float zv = s.u.zF[t * 68 + j];
      float zn = fmaxf(lng[j] * (zv - mu) * rs + lnbe[j], 0.f);
      l0 += zn * c2W[j * 2];
      l1 += zn * c2W[j * 2 + 1];
    }
    out[t * 2]     = l0 + c2b[0];
    out[t * 2 + 1] = l1 + c2b[1];
  }
  if (t == 0) out[256] = rl[0];
}

// ---------------------------------------------------------------------------
extern "C" void kernel_launch(void* const* d_in, const int* in_sizes, int n_in,
                              void* d_out, int out_size, void* d_ws, size_t ws_size,
                              hipStream_t stream) {
  (void)in_sizes; (void)n_in; (void)out_size; (void)ws_size;
  const float* plane_feat  = (const float*)d_in[0];
  const int*   plane_src   = (const int*)d_in[1];
  const int*   plane_dst   = (const int*)d_in[2];
  const int*   patient_src = (const int*)d_in[3];
  const int*   patient_dst = (const int*)d_in[4];
  const float* orig        = (const float*)d_in[5];
  const int*   mask        = (const int*)d_in[6];
  const float* W1   = (const float*)d_in[7];
  const float* al1  = (const float*)d_in[8];
  const float* ar1  = (const float*)d_in[9];
  const float* res1 = (const float*)d_in[10];
  const float* b1   = (const float*)d_in[11];
  const float* g1   = (const float*)d_in[12];
  const float* be1  = (const float*)d_in[13];
  const float* W2   = (const float*)d_in[14];
  const float* al2  = (const float*)d_in[15];
  const float* ar2  = (const float*)d_in[16];
  const float* res2 = (const float*)d_in[17];
  const float* g2   = (const float*)d_in[19];
  const float* be2  = (const float*)d_in[20];
  const float* dW1  = (const float*)d_in[21];
  const float* dg   = (const float*)d_in[23];
  const float* dbe  = (const float*)d_in[24];
  const float* dW2  = (const float*)d_in[25];
  const float* db2  = (const float*)d_in[26];
  const float* ftW  = (const float*)d_in[27];
  const float* ftb  = (const float*)d_in[28];
  const float* ftg  = (const float*)d_in[29];
  const float* ftbe = (const float*)d_in[30];
  const float* gcW  = (const float*)d_in[31];
  const float* gbng = (const float*)d_in[33];
  const float* gbnbe= (const float*)d_in[34];
  const float* c1W  = (const float*)d_in[35];
  const float* c1b  = (const float*)d_in[36];
  const float* lng  = (const float*)d_in[37];
  const float* lnbe = (const float*)d_in[38];
  const float* c2W  = (const float*)d_in[39];
  const float* c2b  = (const float*)d_in[40];

  float* ws   = (float*)d_ws;
  float* rep  = ws;                       // [128][512]
  float* u0   = ws + 65536;               // [128][128]
  float* rl   = ws + 131328;              // [1]
  float* outp = (float*)d_out;

  hipMemsetAsync(rl, 0, sizeof(float), stream);
  plane_enc<<<2048, 256, 0, stream>>>(plane_feat, plane_src, plane_dst,
      W1, al1, ar1, res1, b1, g1, be1, W2, al2, ar2, res2, g2, be2,
      dW1, dg, dbe, dW2, db2, rep, rl);
  k_b1<<<128, 128, 0, stream>>>(orig, rep, ftW, ftb, u0);
  k_patient<<<1, 1024, 0, stream>>>(u0, ftg, ftbe, patient_src, patient_dst, mask,
      gcW, gbng, gbnbe, c1W, c1b, lng, lnbe, c2W, c2b, rl, outp);
}

// Round 4
// 364.827 us; speedup vs baseline: 2.1934x; 1.1001x over previous
//
#include <hip/hip_runtime.h>

#define B_    128
#define P_    16
#define NP_   256
#define EP_   1280
#define EPG_  2048
#define ODIM_ 256
#define NH_   128

typedef __attribute__((ext_vector_type(8))) short s8_t;
typedef __attribute__((ext_vector_type(4))) float f4_t;

__device__ __forceinline__ unsigned short f2b(float x) {
  unsigned u = __builtin_bit_cast(unsigned, x);
  u = (u + 0x7fffu + ((u >> 16) & 1u)) >> 16;
  return (unsigned short)u;
}
__device__ __forceinline__ float b2f(short x) {
  unsigned u = ((unsigned)(unsigned short)x) << 16;
  return __builtin_bit_cast(float, u);
}

// ---------------------------------------------------------------------------
// Stage A: one block (256 thr) per plane graph (2048).  (unchanged from R3)
// ---------------------------------------------------------------------------
struct SmemA {
  float f[256];
  float S0a[256], S1a[256];
  float el2[256], er2[256];
  float abg0[128], abg1[128], abg2[128];
  float al2v[32], ar2v[32];
  __align__(16) unsigned short wT[64 * 136];
  __align__(16) unsigned short z2[256 * 40];
  int cnt[256]; int wtot[4];
  unsigned short esrc[1280];
  float redf[512];
  float scA[32], shA[32];
  float dscA[64], dshA[64];
  float dW2v[128];
  float r8[4][8]; float stat[8]; float wA[2], wB[2];
  float rlacc;
};

__global__ __launch_bounds__(256, 3) void plane_enc(
    const float* __restrict__ feat, const int* __restrict__ esrcg, const int* __restrict__ edstg,
    const float* __restrict__ W1, const float* __restrict__ al1, const float* __restrict__ ar1,
    const float* __restrict__ res1, const float* __restrict__ b1, const float* __restrict__ g1,
    const float* __restrict__ be1,
    const float* __restrict__ W2, const float* __restrict__ al2, const float* __restrict__ ar2,
    const float* __restrict__ res2, const float* __restrict__ g2, const float* __restrict__ be2,
    const float* __restrict__ dW1, const float* __restrict__ dg, const float* __restrict__ dbe,
    const float* __restrict__ dW2, const float* __restrict__ db2,
    float* __restrict__ rep_out, float* __restrict__ rloss_out)
{
  __shared__ SmemA s;
  const int g = blockIdx.x;
  const int p = g & 15;
  const int t = threadIdx.x;
  const int lane = t & 63, wv = t >> 6;
  const int l15 = lane & 15, quad = lane >> 4;

  s.f[t] = feat[g * NP_ + t];
  if (t < 32) { s.al2v[t] = al2[p * 32 + t]; s.ar2v[t] = ar2[p * 32 + t]; }
  if (t == 0) s.rlacc = 0.f;
  s.cnt[t] = 0;
  __syncthreads();

  const int* gs = esrcg + g * EP_;
  const int* gd = edstg + g * EP_;
  for (int k = t; k < EP_; k += 256) atomicAdd(&s.cnt[gd[k]], 1);
  __syncthreads();
  int v = s.cnt[t];
  int incl = v;
  #pragma unroll
  for (int off = 1; off < 64; off <<= 1) {
    int n = __shfl_up(incl, off, 64);
    if (lane >= off) incl += n;
  }
  if (lane == 63) s.wtot[wv] = incl;
  __syncthreads();
  int woff = 0;
  for (int w = 0; w < wv; w++) woff += s.wtot[w];
  const int myStart = woff + incl - v;
  const int myDeg = v;
  __syncthreads();
  s.cnt[t] = myStart;
  __syncthreads();
  for (int k = t; k < EP_; k += 256) {
    int d = gd[k];
    int pos = atomicAdd(&s.cnt[d], 1);
    s.esrc[pos] = (unsigned short)gs[k];
  }
  {
    const float* W2g = W2 + p * 4096;
    const float* Rg  = res2 + p * 4096;
    for (int q = 0; q < 16; q++) {
      int idx = t + 256 * q;
      int k = idx >> 5, n = idx & 31;
      s.wT[n * 136 + k]        = f2b(W2g[idx]);
      s.wT[(n + 32) * 136 + k] = f2b(Rg[idx]);
    }
  }
  if (t < 128) {
    float w1v = W1[p * 128 + t];
    s.el2[t] = w1v * al1[p * 128 + t];
    s.er2[t] = w1v * ar1[p * 128 + t];
  }
  __syncthreads();
  if (t < 2) {
    float a = 0.f, bq = 0.f;
    for (int d2 = 0; d2 < 64; d2++) { a += s.el2[t * 64 + d2]; bq += s.er2[t * 64 + d2]; }
    s.wA[t] = a; s.wB[t] = bq;
  }
  __syncthreads();

  const float fi = s.f[t];
  float S0, S1;
  {
    const float wa0 = s.wA[0], wb0 = s.wB[0], wa1 = s.wA[1], wb1 = s.wB[1];
    float m0 = -1e30f, m1 = -1e30f;
    for (int j = 0; j < myDeg; j++) {
      float fs = s.f[s.esrc[myStart + j]];
      float e0 = wa0 * fs + wb0 * fi; e0 = e0 > 0.f ? e0 : 0.2f * e0;
      float e1 = wa1 * fs + wb1 * fi; e1 = e1 > 0.f ? e1 : 0.2f * e1;
      m0 = fmaxf(m0, e0); m1 = fmaxf(m1, e1);
    }
    float ss0 = 0.f, ss1 = 0.f, U0 = 0.f, U1 = 0.f;
    for (int j = 0; j < myDeg; j++) {
      float fs = s.f[s.esrc[myStart + j]];
      float e0 = wa0 * fs + wb0 * fi; e0 = e0 > 0.f ? e0 : 0.2f * e0;
      float e1 = wa1 * fs + wb1 * fi; e1 = e1 > 0.f ? e1 : 0.2f * e1;
      float x0 = __expf(e0 - m0), x1 = __expf(e1 - m1);
      ss0 += x0; U0 += x0 * fs;
      ss1 += x1; U1 += x1 * fs;
    }
    S0 = U0 / (ss0 + 1e-9f);
    S1 = U1 / (ss1 + 1e-9f);
    s.S0a[t] = S0; s.S1a[t] = S1;
  }

  {
    float vals[8] = {fi, fi * fi, S0, S0 * S0, S0 * fi, S1, S1 * S1, S1 * fi};
    #pragma unroll
    for (int d2 = 32; d2 > 0; d2 >>= 1) {
      #pragma unroll
      for (int q = 0; q < 8; q++) vals[q] += __shfl_down(vals[q], d2, 64);
    }
    if (lane == 0) {
      #pragma unroll
      for (int q = 0; q < 8; q++) s.r8[wv][q] = vals[q];
    }
  }
  __syncthreads();
  if (t < 8) s.stat[t] = (s.r8[0][t] + s.r8[1][t] + s.r8[2][t] + s.r8[3][t]) * (1.f / 256.f);
  __syncthreads();
  if (t < 128) {
    float mf = s.stat[0], ef2 = s.stat[1];
    int hh = t >> 6;
    float mS = s.stat[2 + 3 * hh], eS2 = s.stat[3 + 3 * hh], eSf = s.stat[4 + 3 * hh];
    float varS = eS2 - mS * mS, varf = ef2 - mf * mf, cov = eSf - mS * mf;
    float Wv = W1[p * 128 + t], Rv = res1[p * 128 + t], Bv = b1[p * 128 + t];
    float mu  = Wv * mS + Rv * mf + Bv;
    float var = Wv * Wv * varS + Rv * Rv * varf + 2.f * Wv * Rv * cov;
    float gn  = g1[p * 128 + t] * rsqrtf(var + 1e-5f);
    s.abg0[t] = gn * Wv;
    s.abg1[t] = gn * Rv;
    s.abg2[t] = gn * (Bv - mu) + be1[p * 128 + t];
  }
  __syncthreads();

  float resv[32];
  {
    f4_t accum[4][4];
    #pragma unroll
    for (int i = 0; i < 4; i++)
      #pragma unroll
      for (int nt = 0; nt < 4; nt++) accum[i][nt] = (f4_t){0.f, 0.f, 0.f, 0.f};

    float fm[4], s0m[4], s1m[4];
    #pragma unroll
    for (int i = 0; i < 4; i++) {
      int m = (wv * 4 + i) * 16 + l15;
      fm[i] = s.f[m]; s0m[i] = s.S0a[m]; s1m[i] = s.S1a[m];
    }
    #pragma unroll
    for (int kt = 0; kt < 4; kt++) {
      int cbase = kt * 32 + quad * 8;
      float a0[8], a1[8], a2[8];
      #pragma unroll
      for (int j = 0; j < 8; j++) {
        a0[j] = s.abg0[cbase + j]; a1[j] = s.abg1[cbase + j]; a2[j] = s.abg2[cbase + j];
      }
      s8_t afr[4];
      #pragma unroll
      for (int i = 0; i < 4; i++) {
        float Sm = (kt < 2) ? s0m[i] : s1m[i];
        union { s8_t v; unsigned short u[8]; } fu;
        #pragma unroll
        for (int j = 0; j < 8; j++) {
          float h = fmaxf(fmaf(a0[j], Sm, fmaf(a1[j], fm[i], a2[j])), 0.f);
          fu.u[j] = f2b(h);
        }
        afr[i] = fu.v;
      }
      s8_t bfr[4];
      #pragma unroll
      for (int nt = 0; nt < 4; nt++)
        bfr[nt] = *(const s8_t*)&s.wT[(nt * 16 + l15) * 136 + cbase];
      #pragma unroll
      for (int i = 0; i < 4; i++)
        #pragma unroll
        for (int nt = 0; nt < 4; nt++)
          accum[i][nt] = __builtin_amdgcn_mfma_f32_16x16x32_bf16(afr[i], bfr[nt], accum[i][nt], 0, 0, 0);
    }
    #pragma unroll
    for (int i = 0; i < 4; i++) {
      int mBase = (wv * 4 + i) * 16 + quad * 4;
      #pragma unroll
      for (int nt = 0; nt < 2; nt++) {
        int col = nt * 16 + l15;
        #pragma unroll
        for (int r = 0; r < 4; r++)
          s.z2[(mBase + r) * 40 + col] = f2b(accum[i][nt][r]);
      }
      #pragma unroll
      for (int h2 = 0; h2 < 2; h2++)
        #pragma unroll
        for (int r = 0; r < 4; r++)
          resv[(i * 2 + h2) * 4 + r] = accum[i][2 + h2][r];
    }
  }
  __syncthreads();

  {
    const s8_t* zr = (const s8_t*)&s.z2[t * 40];
    float el = 0.f, er = 0.f;
    #pragma unroll
    for (int q = 0; q < 4; q++) {
      s8_t vz = zr[q];
      #pragma unroll
      for (int j = 0; j < 8; j++) {
        float zv = b2f(vz[j]);
        el += zv * s.al2v[q * 8 + j];
        er += zv * s.ar2v[q * 8 + j];
      }
    }
    s.el2[t] = el; s.er2[t] = er;
  }
  {
    const float* Dg = dW1 + p * 4096;
    for (int q = 0; q < 16; q++) {
      int idx = t + 256 * q;
      int k = idx >> 7, n = idx & 127;
      s.wT[n * 40 + k] = f2b(Dg[idx]);
    }
    if (t < 128) s.dW2v[t] = dW2[p * 128 + t];
  }
  const float db2v = db2[p];
  __syncthreads();

  float hrow[32];
  {
    const float eri = s.er2[t];
    float m = -1e30f;
    for (int j = 0; j < myDeg; j++) {
      float e = s.el2[s.esrc[myStart + j]] + eri;
      e = e > 0.f ? e : 0.2f * e;
      m = fmaxf(m, e);
    }
    float ss = 0.f;
    #pragma unroll
    for (int d2 = 0; d2 < 32; d2++) hrow[d2] = 0.f;
    for (int j = 0; j < myDeg; j++) {
      int sj = s.esrc[myStart + j];
      float e = s.el2[sj] + eri;
      e = e > 0.f ? e : 0.2f * e;
      float x = __expf(e - m);
      ss += x;
      const s8_t* zr = (const s8_t*)&s.z2[sj * 40];
      #pragma unroll
      for (int q = 0; q < 4; q++) {
        s8_t vz = zr[q];
        #pragma unroll
        for (int jj = 0; jj < 8; jj++) hrow[q * 8 + jj] += x * b2f(vz[jj]);
      }
    }
    float inv = 1.f / (ss + 1e-9f);
    #pragma unroll
    for (int d2 = 0; d2 < 32; d2++) hrow[d2] *= inv;
  }
  __syncthreads();
  #pragma unroll
  for (int i = 0; i < 4; i++) {
    int mBase = (wv * 4 + i) * 16 + quad * 4;
    #pragma unroll
    for (int h2 = 0; h2 < 2; h2++) {
      int col = h2 * 16 + l15;
      #pragma unroll
      for (int r = 0; r < 4; r++)
        s.z2[(mBase + r) * 40 + col] = f2b(resv[(i * 2 + h2) * 4 + r]);
    }
  }
  __syncthreads();
  {
    const s8_t* zr = (const s8_t*)&s.z2[t * 40];
    #pragma unroll
    for (int q = 0; q < 4; q++) {
      s8_t vz = zr[q];
      #pragma unroll
      for (int jj = 0; jj < 8; jj++) hrow[q * 8 + jj] += b2f(vz[jj]);
    }
  }
  #pragma unroll
  for (int d2 = 0; d2 < 32; d2++) s.z2[t * 40 + d2] = f2b(hrow[d2]);
  __syncthreads();

  {
    int c = t & 31, gq = t >> 5;
    float s1 = 0.f, s2 = 0.f;
    for (int j = 0; j < 32; j++) {
      float vz = b2f((short)s.z2[(gq * 32 + j) * 40 + c]);
      s1 += vz; s2 += vz * vz;
    }
    s.redf[t] = s1; s.redf[256 + t] = s2;
  }
  __syncthreads();
  if (t < 32) {
    float s1 = 0.f, s2 = 0.f;
    #pragma unroll
    for (int q = 0; q < 8; q++) { s1 += s.redf[q * 32 + t]; s2 += s.redf[256 + q * 32 + t]; }
    float mu = s1 * (1.f / 256.f);
    float var = s2 * (1.f / 256.f) - mu * mu;
    float a = g2[p * 32 + t] * rsqrtf(var + 1e-5f);
    s.scA[t] = a; s.shA[t] = be2[p * 32 + t] - a * mu;
  }
  __syncthreads();
  {
    int c = t & 31, gq = t >> 5;
    float a = s.scA[c], bb = s.shA[c];
    float s1 = 0.f;
    for (int j = 0; j < 32; j++) {
      int ad = (gq * 32 + j) * 40 + c;
      float vz = b2f((short)s.z2[ad]);
      float hv = fmaxf(a * vz + bb, 0.f);
      s.z2[ad] = f2b(hv);
      s1 += hv;
    }
    s.redf[t] = s1;
  }
  __syncthreads();
  if (t < 32) {
    float s1 = 0.f;
    #pragma unroll
    for (int q = 0; q < 8; q++) s1 += s.redf[q * 32 + t];
    rep_out[g * 32 + t] = s1 * (1.f / 256.f);
  }
  __syncthreads();

  {
    s8_t afr2[4];
    #pragma unroll
    for (int i = 0; i < 4; i++)
      afr2[i] = *(const s8_t*)&s.z2[((wv * 4 + i) * 16 + l15) * 40 + quad * 8];
    float rAcc[4][4];
    #pragma unroll
    for (int i = 0; i < 4; i++)
      #pragma unroll
      for (int r = 0; r < 4; r++) rAcc[i][r] = 0.f;

    for (int half = 0; half < 2; half++) {
      __syncthreads();
      s.redf[t] = 0.f; s.redf[256 + t] = 0.f;
      __syncthreads();
      f4_t acc2[4][4];
      #pragma unroll
      for (int i = 0; i < 4; i++)
        #pragma unroll
        for (int nt = 0; nt < 4; nt++) acc2[i][nt] = (f4_t){0.f, 0.f, 0.f, 0.f};
      s8_t bfr[4];
      #pragma unroll
      for (int nt = 0; nt < 4; nt++)
        bfr[nt] = *(const s8_t*)&s.wT[(half * 64 + nt * 16 + l15) * 40 + quad * 8];
      #pragma unroll
      for (int i = 0; i < 4; i++)
        #pragma unroll
        for (int nt = 0; nt < 4; nt++)
          acc2[i][nt] = __builtin_amdgcn_mfma_f32_16x16x32_bf16(afr2[i], bfr[nt], acc2[i][nt], 0, 0, 0);
      #pragma unroll
      for (int nt = 0; nt < 4; nt++) {
        float s1 = 0.f, s2 = 0.f;
        #pragma unroll
        for (int i = 0; i < 4; i++)
          #pragma unroll
          for (int r = 0; r < 4; r++) { float vv = acc2[i][nt][r]; s1 += vv; s2 += vv * vv; }
        atomicAdd(&s.redf[nt * 16 + l15], s1);
        atomicAdd(&s.redf[256 + nt * 16 + l15], s2);
      }
      __syncthreads();
      if (t < 64) {
        int col = half * 64 + t;
        float mu = s.redf[t] * (1.f / 256.f);
        float var = s.redf[256 + t] * (1.f / 256.f) - mu * mu;
        float a = dg[p * 128 + col] * rsqrtf(var + 1e-5f);
        s.dscA[t] = a; s.dshA[t] = dbe[p * 128 + col] - a * mu;
      }
      __syncthreads();
      #pragma unroll
      for (int nt = 0; nt < 4; nt++) {
        int cl = nt * 16 + l15;
        float a = s.dscA[cl], bb = s.dshA[cl], w2 = s.dW2v[half * 64 + cl];
        #pragma unroll
        for (int i = 0; i < 4; i++)
          #pragma unroll
          for (int r = 0; r < 4; r++) {
            float dv = fmaxf(a * acc2[i][nt][r] + bb, 0.f);
            rAcc[i][r] += dv * w2;
          }
      }
    }
    #pragma unroll
    for (int off = 1; off < 16; off <<= 1)
      #pragma unroll
      for (int i = 0; i < 4; i++)
        #pragma unroll
        for (int r = 0; r < 4; r++) rAcc[i][r] += __shfl_xor(rAcc[i][r], off, 64);
    if (l15 == 0) {
      float sq = 0.f;
      #pragma unroll
      for (int i = 0; i < 4; i++)
        #pragma unroll
        for (int r = 0; r < 4; r++) {
          int m = (wv * 4 + i) * 16 + quad * 4 + r;
          float diff = rAcc[i][r] + db2v - s.f[m];
          sq += diff * diff;
        }
      atomicAdd(&s.rlacc, sq);
    }
  }
  __syncthreads();
  if (t == 0) atomicAdd(rloss_out, s.rlacc * (1.f / (256.f * 2048.f)));
}

// ---------------------------------------------------------------------------
// Fused patient stage v2: ONE block, 1024 threads (16 waves), all-MFMA.
// Key identity: masked GC aggregation == dense matmul with
//   Abar[d][s] = count(s->d) * mask[d]*mask[s] * rsqrt(din[d]) * rsqrt(dout[s]).
// ft matmul (K=768) folded in; h residual chain kept in fp32 registers
// (MFMA-C ownership); hT bf16 is the inter-wave communication copy.
// ---------------------------------------------------------------------------
struct SmemB {
  __align__(16) unsigned short arow[128 * 136];  // Abar bf16, rows=dst
  __align__(16) unsigned short hT[128 * 136];    // h^T bf16 [feature][patient]
  union {
    float aB[128 * 132];                          // fp32 count-matrix build
    struct {
      union {
        __align__(16) unsigned short wT[128 * 136]; // B^T staging (ftW/gcW/c1W)
        float zF[128 * 68];                         // cls pre-LN
      } w;
      __align__(16) unsigned short aggB[128 * 136]; // agg / hsum A-operand
    } mm;
  } u;
  float redA[1024], redB[1024];
  float facs[128], facd[128], scB[128], shB[128];
  int co[128], ci[128];
};

__global__ __launch_bounds__(1024) void k_patient(
    const float* __restrict__ orig, const float* __restrict__ rep,
    const float* __restrict__ ftW, const float* __restrict__ ftg, const float* __restrict__ ftbe,
    const int* __restrict__ ps, const int* __restrict__ pd, const int* __restrict__ mask,
    const float* __restrict__ gcW, const float* __restrict__ gbng, const float* __restrict__ gbnbe,
    const float* __restrict__ c1W, const float* __restrict__ c1b,
    const float* __restrict__ lng, const float* __restrict__ lnbe,
    const float* __restrict__ c2W, const float* __restrict__ c2b,
    const float* __restrict__ rl, float* __restrict__ out)
{
  __shared__ SmemB s;
  const int t = threadIdx.x;
  const int w = t >> 6, lane = t & 63;
  const int l15 = lane & 15, quad = lane >> 4;
  const int mb = w & 7, nb = (w >> 3) * 64;

  // ---- phase 1: degrees + Abar ---------------------------------------------
  if (t < 128) { s.co[t] = 0; s.ci[t] = 0; }
  for (int idx = t; idx < 128 * 132; idx += 1024) s.u.aB[idx] = 0.f;
  __syncthreads();
  for (int e = t; e < EPG_; e += 1024) { atomicAdd(&s.co[ps[e]], 1); atomicAdd(&s.ci[pd[e]], 1); }
  __syncthreads();
  if (t < 128) {
    float mk = (float)mask[t];
    int da = s.co[t] > 1 ? s.co[t] : 1;
    int db = s.ci[t] > 1 ? s.ci[t] : 1;
    s.facs[t] = mk * rsqrtf((float)da);
    s.facd[t] = mk * rsqrtf((float)db);
  }
  for (int e = t; e < EPG_; e += 1024) atomicAdd(&s.u.aB[pd[e] * 132 + ps[e]], 1.f);
  __syncthreads();
  for (int idx = t; idx < 16384; idx += 1024) {
    int d = idx >> 7, sN = idx & 127;
    s.arow[d * 136 + sN] = f2b(s.u.aB[d * 132 + sN] * s.facd[d] * s.facs[sN]);
  }
  __syncthreads();

  // ---- phase 2: ft matmul (M=128, N=128, K=768 in 6 chunks) ----------------
  f4_t acc[4];
  #pragma unroll
  for (int nt = 0; nt < 4; nt++) acc[nt] = (f4_t){0.f, 0.f, 0.f, 0.f};
  const int m = mb * 16 + l15;
  for (int chunk = 0; chunk < 6; chunk++) {
    #pragma unroll
    for (int q = 0; q < 16; q++) {
      int idx = t + 1024 * q;
      int kk = idx >> 7, n = idx & 127;
      s.u.mm.w.wT[n * 136 + kk] = f2b(ftW[(chunk * 128 + kk) * 128 + n]);
    }
    __syncthreads();
    #pragma unroll
    for (int ks = 0; ks < 4; ks++) {
      int k0 = chunk * 128 + ks * 32 + quad * 8;
      const float* px = (k0 < 256) ? (orig + m * 256 + k0) : (rep + m * 512 + (k0 - 256));
      float4 xa = ((const float4*)px)[0];
      float4 xb = ((const float4*)px)[1];
      union { s8_t v; unsigned short u[8]; } fu;
      fu.u[0] = f2b(xa.x); fu.u[1] = f2b(xa.y); fu.u[2] = f2b(xa.z); fu.u[3] = f2b(xa.w);
      fu.u[4] = f2b(xb.x); fu.u[5] = f2b(xb.y); fu.u[6] = f2b(xb.z); fu.u[7] = f2b(xb.w);
      #pragma unroll
      for (int nt = 0; nt < 4; nt++) {
        s8_t bfr = *(const s8_t*)&s.u.mm.w.wT[(nb + nt * 16 + l15) * 136 + ks * 32 + quad * 8];
        acc[nt] = __builtin_amdgcn_mfma_f32_16x16x32_bf16(fu.v, bfr, acc[nt], 0, 0, 0);
      }
    }
    __syncthreads();
  }

  // ---- BN(ft) + relu -> h (fp32 regs) + hT bf16 ----------------------------
  float hR[16], hsumR[16];
  {
    #pragma unroll
    for (int nt = 0; nt < 4; nt++) {
      float s1 = acc[nt][0] + acc[nt][1] + acc[nt][2] + acc[nt][3];
      float s2 = acc[nt][0]*acc[nt][0] + acc[nt][1]*acc[nt][1] + acc[nt][2]*acc[nt][2] + acc[nt][3]*acc[nt][3];
      s1 += __shfl_xor(s1, 16, 64); s1 += __shfl_xor(s1, 32, 64);
      s2 += __shfl_xor(s2, 16, 64); s2 += __shfl_xor(s2, 32, 64);
      if (quad == 0) {
        s.redA[mb * 128 + nb + nt * 16 + l15] = s1;
        s.redB[mb * 128 + nb + nt * 16 + l15] = s2;
      }
    }
    __syncthreads();
    if (t < 128) {
      float a1 = 0.f, a2 = 0.f;
      #pragma unroll
      for (int q = 0; q < 8; q++) { a1 += s.redA[q * 128 + t]; a2 += s.redB[q * 128 + t]; }
      float mu = a1 * (1.f / 128.f), var = a2 * (1.f / 128.f) - mu * mu;
      float a = ftg[t] * rsqrtf(var + 1e-5f);
      s.scB[t] = a; s.shB[t] = ftbe[t] - a * mu;
    }
    __syncthreads();
    #pragma unroll
    for (int nt = 0; nt < 4; nt++) {
      int col = nb + nt * 16 + l15;
      float a = s.scB[col], bb = s.shB[col];
      #pragma unroll
      for (int r = 0; r < 4; r++) {
        int row = mb * 16 + quad * 4 + r;
        float hv = fmaxf(a * acc[nt][r] + bb, 0.f);
        hR[nt * 4 + r] = hv; hsumR[nt * 4 + r] = hv;
        s.hT[col * 136 + row] = f2b(hv);
      }
    }
  }
  __syncthreads();

  // ---- 3 GC layers (two MFMAs each) ----------------------------------------
  for (int layer = 0; layer < 3; layer++) {
    // stage gcW^T + agg = Abar @ h
    #pragma unroll
    for (int q = 0; q < 16; q++) {
      int idx = t + 1024 * q;
      int kk = idx >> 7, n = idx & 127;
      s.u.mm.w.wT[n * 136 + kk] = f2b(gcW[layer * 16384 + kk * 128 + n]);
    }
    f4_t ag[4];
    #pragma unroll
    for (int nt = 0; nt < 4; nt++) ag[nt] = (f4_t){0.f, 0.f, 0.f, 0.f};
    #pragma unroll
    for (int ks = 0; ks < 4; ks++) {
      s8_t afr = *(const s8_t*)&s.arow[(mb * 16 + l15) * 136 + ks * 32 + quad * 8];
      #pragma unroll
      for (int nt = 0; nt < 4; nt++) {
        s8_t bfr = *(const s8_t*)&s.hT[(nb + nt * 16 + l15) * 136 + ks * 32 + quad * 8];
        ag[nt] = __builtin_amdgcn_mfma_f32_16x16x32_bf16(afr, bfr, ag[nt], 0, 0, 0);
      }
    }
    #pragma unroll
    for (int nt = 0; nt < 4; nt++) {
      int col = nb + nt * 16 + l15;
      #pragma unroll
      for (int r = 0; r < 4; r++)
        s.u.mm.aggB[(mb * 16 + quad * 4 + r) * 136 + col] = f2b(ag[nt][r]);
    }
    __syncthreads();
    // o = agg @ W
    f4_t oc[4];
    #pragma unroll
    for (int nt = 0; nt < 4; nt++) oc[nt] = (f4_t){0.f, 0.f, 0.f, 0.f};
    #pragma unroll
    for (int ks = 0; ks < 4; ks++) {
      s8_t afr = *(const s8_t*)&s.u.mm.aggB[(mb * 16 + l15) * 136 + ks * 32 + quad * 8];
      #pragma unroll
      for (int nt = 0; nt < 4; nt++) {
        s8_t bfr = *(const s8_t*)&s.u.mm.w.wT[(nb + nt * 16 + l15) * 136 + ks * 32 + quad * 8];
        oc[nt] = __builtin_amdgcn_mfma_f32_16x16x32_bf16(afr, bfr, oc[nt], 0, 0, 0);
      }
    }
    // BN stats
    #pragma unroll
    for (int nt = 0; nt < 4; nt++) {
      float s1 = oc[nt][0] + oc[nt][1] + oc[nt][2] + oc[nt][3];
      float s2 = oc[nt][0]*oc[nt][0] + oc[nt][1]*oc[nt][1] + oc[nt][2]*oc[nt][2] + oc[nt][3]*oc[nt][3];
      s1 += __shfl_xor(s1, 16, 64); s1 += __shfl_xor(s1, 32, 64);
      s2 += __shfl_xor(s2, 16, 64); s2 += __shfl_xor(s2, 32, 64);
      if (quad == 0) {
        s.redA[mb * 128 + nb + nt * 16 + l15] = s1;
        s.redB[mb * 128 + nb + nt * 16 + l15] = s2;
      }
    }
    __syncthreads();
    if (t < 128) {
      float a1 = 0.f, a2 = 0.f;
      #pragma unroll
      for (int q = 0; q < 8; q++) { a1 += s.redA[q * 128 + t]; a2 += s.redB[q * 128 + t]; }
      float mu = a1 * (1.f / 128.f), var = a2 * (1.f / 128.f) - mu * mu;
      float a = gbng[layer * 128 + t] * rsqrtf(var + 1e-5f);
      s.scB[t] = a; s.shB[t] = gbnbe[layer * 128 + t] - a * mu;
    }
    __syncthreads();
    #pragma unroll
    for (int nt = 0; nt < 4; nt++) {
      int col = nb + nt * 16 + l15;
      float a = s.scB[col], bb = s.shB[col];
      #pragma unroll
      for (int r = 0; r < 4; r++) {
        int row = mb * 16 + quad * 4 + r;
        float hn = fmaxf(a * oc[nt][r] + bb, 0.f) + hR[nt * 4 + r];
        hR[nt * 4 + r] = hn;
        hsumR[nt * 4 + r] += hn;
        s.hT[col * 136 + row] = f2b(hn);
      }
    }
    __syncthreads();
  }

  // ---- classifier ----------------------------------------------------------
  #pragma unroll
  for (int nt = 0; nt < 4; nt++) {
    int col = nb + nt * 16 + l15;
    #pragma unroll
    for (int r = 0; r < 4; r++)
      s.u.mm.aggB[(mb * 16 + quad * 4 + r) * 136 + col] = f2b(hsumR[nt * 4 + r] * 0.25f);
  }
  #pragma unroll
  for (int q = 0; q < 8; q++) {
    int idx = t + 1024 * q;
    int n = idx & 63, kk = idx >> 6;
    s.u.mm.w.wT[n * 136 + kk] = f2b(c1W[kk * 64 + n]);
  }
  __syncthreads();
  {
    const int nb2 = (w >> 3) * 32;
    f4_t zc[2];
    #pragma unroll
    for (int nt = 0; nt < 2; nt++) zc[nt] = (f4_t){0.f, 0.f, 0.f, 0.f};
    #pragma unroll
    for (int ks = 0; ks < 4; ks++) {
      s8_t afr = *(const s8_t*)&s.u.mm.aggB[(mb * 16 + l15) * 136 + ks * 32 + quad * 8];
      #pragma unroll
      for (int nt = 0; nt < 2; nt++) {
        s8_t bfr = *(const s8_t*)&s.u.mm.w.wT[(nb2 + nt * 16 + l15) * 136 + ks * 32 + quad * 8];
        zc[nt] = __builtin_amdgcn_mfma_f32_16x16x32_bf16(afr, bfr, zc[nt], 0, 0, 0);
      }
    }
    __syncthreads();   // wT reads done before zF (same bytes) writes
    #pragma unroll
    for (int nt = 0; nt < 2; nt++) {
      int col = nb2 + nt * 16 + l15;
      #pragma unroll
      for (int r = 0; r < 4; r++)
        s.u.mm.w.zF[(mb * 16 + quad * 4 + r) * 68 + col] = zc[nt][r] + c1b[col];
    }
  }
  __syncthreads();
  if (t < 128) {
    float s1 = 0.f, s2 = 0.f;
    #pragma unroll
    for (int j = 0; j < 64; j++) { float zv = s.u.mm.w.zF[t * 68 + j]; s1 += zv; s2 += zv * zv; }
    float mu = s1 * (1.f / 64.f);
    float var = s2 * (1.f / 64.f) - mu * mu;
    float rs = rsqrtf(var + 1e-5f);
    float l0 = 0.f, l1 = 0.f;
    #pragma unroll
    for (int j = 0; j < 64; j++) {
      float zv = s.u.mm.w.zF[t * 68 + j];
      float zn = fmaxf(lng[j] * (zv - mu) * rs + lnbe[j], 0.f);
      l0 += zn * c2W[j * 2];
      l1 += zn * c2W[j * 2 + 1];
    }
    out[t * 2]     = l0 + c2b[0];
    out[t * 2 + 1] = l1 + c2b[1];
  }
  if (t == 0) out[256] = rl[0];
}

// ---------------------------------------------------------------------------
extern "C" void kernel_launch(void* const* d_in, const int* in_sizes, int n_in,
                              void* d_out, int out_size, void* d_ws, size_t ws_size,
                              hipStream_t stream) {
  (void)in_sizes; (void)n_in; (void)out_size; (void)ws_size;
  const float* plane_feat  = (const float*)d_in[0];
  const int*   plane_src   = (const int*)d_in[1];
  const int*   plane_dst   = (const int*)d_in[2];
  const int*   patient_src = (const int*)d_in[3];
  const int*   patient_dst = (const int*)d_in[4];
  const float* orig        = (const float*)d_in[5];
  const int*   mask        = (const int*)d_in[6];
  const float* W1   = (const float*)d_in[7];
  const float* al1  = (const float*)d_in[8];
  const float* ar1  = (const float*)d_in[9];
  const float* res1 = (const float*)d_in[10];
  const float* b1   = (const float*)d_in[11];
  const float* g1   = (const float*)d_in[12];
  const float* be1  = (const float*)d_in[13];
  const float* W2   = (const float*)d_in[14];
  const float* al2  = (const float*)d_in[15];
  const float* ar2  = (const float*)d_in[16];
  const float* res2 = (const float*)d_in[17];
  const float* g2   = (const float*)d_in[19];
  const float* be2  = (const float*)d_in[20];
  const float* dW1  = (const float*)d_in[21];
  const float* dg   = (const float*)d_in[23];
  const float* dbe  = (const float*)d_in[24];
  const float* dW2  = (const float*)d_in[25];
  const float* db2  = (const float*)d_in[26];
  const float* ftW  = (const float*)d_in[27];
  const float* ftg  = (const float*)d_in[29];
  const float* ftbe = (const float*)d_in[30];
  const float* gcW  = (const float*)d_in[31];
  const float* gbng = (const float*)d_in[33];
  const float* gbnbe= (const float*)d_in[34];
  const float* c1W  = (const float*)d_in[35];
  const float* c1b  = (const float*)d_in[36];
  const float* lng  = (const float*)d_in[37];
  const float* lnbe = (const float*)d_in[38];
  const float* c2W  = (const float*)d_in[39];
  const float* c2b  = (const float*)d_in[40];

  float* ws   = (float*)d_ws;
  float* rep  = ws;                       // [128][512]
  float* rl   = ws + 131328;              // [1]
  float* outp = (float*)d_out;

  hipMemsetAsync(rl, 0, sizeof(float), stream);
  plane_enc<<<2048, 256, 0, stream>>>(plane_feat, plane_src, plane_dst,
      W1, al1, ar1, res1, b1, g1, be1, W2, al2, ar2, res2, g2, be2,
      dW1, dg, dbe, dW2, db2, rep, rl);
  k_patient<<<1, 1024, 0, stream>>>(orig, rep, ftW, ftg, ftbe,
      patient_src, patient_dst, mask,
      gcW, gbng, gbnbe, c1W, c1b, lng, lnbe, c2W, c2b, rl, outp);
}